// Round 9
// baseline (556.244 us; speedup 1.0000x reference)
//
#include <hip/hip_runtime.h>
#include <hip/hip_bf16.h>

static constexpr int N_ = 50000;
static constexpr int E_ = 800000;

// ================= shared GEMM building blocks (128 nodes x 64 cols tile) =================
// 256 thr: col=tid&7 (8 output quads), rowb=tid>>3 (32 rows); nodes rowb+32*i.
// At4 pitch 129 float4 -> conflict-free fragment reads. kg-loop NOT unrolled (spill guard).

#define GEMM_FMA_BLOCK(AV, W0, W1, ROW)                                              \
      acc[ROW][0]=fmaf(AV,W0.x,acc[ROW][0]); acc[ROW][1]=fmaf(AV,W0.y,acc[ROW][1]);  \
      acc[ROW][2]=fmaf(AV,W0.z,acc[ROW][2]); acc[ROW][3]=fmaf(AV,W0.w,acc[ROW][3]);  \
      acc[ROW][4]=fmaf(AV,W1.x,acc[ROW][4]); acc[ROW][5]=fmaf(AV,W1.y,acc[ROW][5]);  \
      acc[ROW][6]=fmaf(AV,W1.z,acc[ROW][6]); acc[ROW][7]=fmaf(AV,W1.w,acc[ROW][7]);

#define GEMM_KLOOP(KQc)                                                              \
  _Pragma("unroll 1")                                                                \
  for (int kg = 0; kg < (KQc); ++kg) {                                               \
    float4 a0 = At4[kg * 129 + rowb];                                                \
    float4 a1 = At4[kg * 129 + rowb + 32];                                           \
    float4 a2 = At4[kg * 129 + rowb + 64];                                           \
    float4 a3 = At4[kg * 129 + rowb + 96];                                           \
    _Pragma("unroll")                                                                \
    for (int t = 0; t < 4; ++t) {                                                    \
      float4 w0 = *(const float4*)(Wt + (kg * 4 + t) * 64 + j0);                     \
      float4 w1 = *(const float4*)(Wt + (kg * 4 + t) * 64 + j0 + 4);                 \
      float av0 = t==0?a0.x:t==1?a0.y:t==2?a0.z:a0.w;                                \
      float av1 = t==0?a1.x:t==1?a1.y:t==2?a1.z:a1.w;                                \
      float av2 = t==0?a2.x:t==1?a2.y:t==2?a2.z:a2.w;                                \
      float av3 = t==0?a3.x:t==1?a3.y:t==2?a3.z:a3.w;                                \
      GEMM_FMA_BLOCK(av0, w0, w1, 0)                                                 \
      GEMM_FMA_BLOCK(av1, w0, w1, 1)                                                 \
      GEMM_FMA_BLOCK(av2, w0, w1, 2)                                                 \
      GEMM_FMA_BLOCK(av3, w0, w1, 3)                                                 \
    }                                                                                \
  }

#define ACC_INIT(BPTR)                                                               \
  {                                                                                  \
    float4 b0v = *(const float4*)((BPTR) + j0);                                      \
    float4 b1v = *(const float4*)((BPTR) + j0 + 4);                                  \
    _Pragma("unroll")                                                                \
    for (int i = 0; i < 4; ++i) {                                                    \
      acc[i][0]=b0v.x; acc[i][1]=b0v.y; acc[i][2]=b0v.z; acc[i][3]=b0v.w;            \
      acc[i][4]=b1v.x; acc[i][5]=b1v.y; acc[i][6]=b1v.z; acc[i][7]=b1v.w;            \
    }                                                                                \
  }

#define STAGE_W(WPTR, LDW, KPADc, KREAL)                                             \
  for (int idx = tid; idx < (KPADc) * 16; idx += 256) {                              \
    int k = idx >> 4, jq = idx & 15;                                                 \
    float4 v = (k < (KREAL)) ? *(const float4*)((WPTR) + (size_t)k * (LDW) + jq * 4) \
                             : make_float4(0.f, 0.f, 0.f, 0.f);                      \
    *(float4*)(Wt + k * 64 + jq * 4) = v;                                            \
  }

#define STAGE_A(APTR, LDA, KQc)                                                      \
  for (int idx = tid; idx < 128 * (KQc); idx += 256) {                               \
    int r = idx / (KQc), kq = idx - r * (KQc);                                       \
    int node = nb + r;                                                               \
    float4 v = (node < N_) ? *(const float4*)((APTR) + (size_t)node * (LDA) + kq * 4)\
                           : make_float4(0.f, 0.f, 0.f, 0.f);                        \
    At4[kq * 129 + r] = v;                                                           \
  }

#define STORE_C(CPTR, LDC, RELUc, ACCc)                                              \
  _Pragma("unroll")                                                                  \
  for (int i = 0; i < 4; ++i) {                                                      \
    int node = nb + rowb + 32 * i;                                                   \
    if (node < N_) {                                                                 \
      float* cp = (CPTR) + (size_t)node * (LDC) + j0;                                \
      float o0=acc[i][0],o1=acc[i][1],o2=acc[i][2],o3=acc[i][3];                     \
      float o4=acc[i][4],o5=acc[i][5],o6=acc[i][6],o7=acc[i][7];                     \
      if (RELUc) { o0=fmaxf(o0,0.f);o1=fmaxf(o1,0.f);o2=fmaxf(o2,0.f);o3=fmaxf(o3,0.f); \
                   o4=fmaxf(o4,0.f);o5=fmaxf(o5,0.f);o6=fmaxf(o6,0.f);o7=fmaxf(o7,0.f); } \
      if (ACCc) { float4 c0=*(const float4*)cp; float4 c1=*(const float4*)(cp+4);    \
                  o0+=c0.x;o1+=c0.y;o2+=c0.z;o3+=c0.w;o4+=c1.x;o5+=c1.y;o6+=c1.z;o7+=c1.w; } \
      *(float4*)cp = make_float4(o0,o1,o2,o3);                                       \
      *(float4*)(cp+4) = make_float4(o4,o5,o6,o7);                                   \
    }                                                                                \
  }

// ---------------- CSR build ----------------
__global__ void k_hist(const int* __restrict__ ei, int* __restrict__ deg) {
  int e = blockIdx.x * blockDim.x + threadIdx.x;
  if (e < E_) atomicAdd(&deg[ei[E_ + e]], 1);
}

__global__ __launch_bounds__(1024) void k_scan_blk(const int* __restrict__ deg,
                                                   int* __restrict__ off,
                                                   int* __restrict__ bsum) {
  __shared__ int sm[1024];
  int t = threadIdx.x;
  int i = blockIdx.x * 1024 + t;
  int v = (i < N_) ? deg[i] : 0;
  sm[t] = v;
  __syncthreads();
  for (int s = 1; s < 1024; s <<= 1) {
    int u = (t >= s) ? sm[t - s] : 0;
    __syncthreads();
    sm[t] += u;
    __syncthreads();
  }
  if (i < N_) off[i] = sm[t] - v;
  if (t == 1023) bsum[blockIdx.x] = sm[t];
}

__global__ void k_scan_top(int* __restrict__ bsum, int nb) {
  int t = threadIdx.x;  // 64
  int v = (t < nb) ? bsum[t] : 0;
  int orig = v;
  for (int s = 1; s < 64; s <<= 1) {
    int u = __shfl_up(v, s);
    if (t >= s) v += u;
  }
  if (t < nb) bsum[t] = v - orig;
}

__global__ void k_scan_add(int* __restrict__ off, const int* __restrict__ bsum,
                           int* __restrict__ cur) {
  int i = blockIdx.x * blockDim.x + threadIdx.x;
  if (i < N_) {
    int o = off[i] + bsum[i >> 10];
    off[i] = o;
    cur[i] = o;
  }
  if (i == 0) off[N_] = E_;
}

// Scatter edge to CSR slot; ALSO record pos[e]=p (coalesced by e) for the final
// alpha permute.
__global__ void k_scatter(const int* __restrict__ ei, int* __restrict__ cursor,
                          int2* __restrict__ csr_es, int* __restrict__ pos) {
  int e = blockIdx.x * blockDim.x + threadIdx.x;
  if (e < E_) {
    int s = ei[e];
    int d = ei[E_ + e];
    int p = atomicAdd(&cursor[d], 1);
    csr_es[p] = make_int2(e, s);
    pos[e] = p;
  }
}

// Streaming permute of edge_attr into CSR order (random 24B eattr read paid ONCE).
__global__ void k_eaperm(const int2* __restrict__ csr_es, const float* __restrict__ eattr,
                         float4* __restrict__ eaA, float2* __restrict__ eaB) {
  int p = blockIdx.x * blockDim.x + threadIdx.x;
  if (p < E_) {
    int e = csr_es[p].x;
    const float* ep = eattr + (size_t)e * 6;
    eaA[p] = make_float4(ep[0], ep[1], ep[2], ep[3]);
    eaB[p] = make_float2(ep[4], ep[5]);
  }
}

// Final alpha materialization: alpha[e][h] = exP[pos[e]][h] * dinv[dst[e]][h].
// dinv is PER-HEAD (R8 bug: stored only head 0's). Writes coalesced by e; exP/dinvN
// random reads hit L3-resident buffers (12.8 MB + 0.8 MB).
__global__ void k_alpha(const int* __restrict__ pos, const int* __restrict__ dei,
                        const float* __restrict__ exP, const float* __restrict__ dinvN,
                        float* __restrict__ alpha) {
  int e = blockIdx.x * blockDim.x + threadIdx.x;
  if (e < E_) {
    int p = pos[e];
    int d = dei[e];
    float4 di = *(const float4*)(dinvN + (size_t)d * 4);
    float4 x4 = *(const float4*)(exP + (size_t)p * 4);
    *(float4*)(alpha + (size_t)e * 4) =
        make_float4(x4.x * di.x, x4.y * di.y, x4.z * di.z, x4.w * di.w);
  }
}

// ---------------- Fused encoder: relu(X24@W1+b1)@W2+b2 in ONE kernel ----------------
__device__ __forceinline__ float encval(int c, int node, int nt, int sd,
                                        const float* __restrict__ x,
                                        const float* __restrict__ temb,
                                        const float* __restrict__ semb) {
  if (c < 7) return x[node * 7 + c];
  if (c < 15) return temb[nt * 8 + c - 7];
  if (c < 23) return semb[sd * 8 + c - 15];
  return 0.f;
}

__global__ __launch_bounds__(256, 3) void k_enc(
    const float* __restrict__ x, const int* __restrict__ ntype, const int* __restrict__ sid,
    const float* __restrict__ temb, const float* __restrict__ semb,
    const float* __restrict__ w1, const float* __restrict__ b1,
    const float* __restrict__ w2, const float* __restrict__ b2,
    float* __restrict__ hout) {
  __shared__ float4 At4[16 * 129];   // phase1 uses rows kq=0..5; phase2 all 16
  __shared__ float Wt[64 * 64];
  int tid = threadIdx.x;
  int nb = blockIdx.x * 128;
  for (int idx = tid; idx < 128 * 6; idx += 256) {
    int r = idx / 6, kq = idx - r * 6;
    int node = nb + r;
    float v0 = 0.f, v1 = 0.f, v2 = 0.f, v3 = 0.f;
    if (node < N_) {
      int nt = ntype[node], sd = sid[node];
      int c = kq * 4;
      v0 = encval(c, node, nt, sd, x, temb, semb);
      v1 = encval(c + 1, node, nt, sd, x, temb, semb);
      v2 = encval(c + 2, node, nt, sd, x, temb, semb);
      v3 = encval(c + 3, node, nt, sd, x, temb, semb);
    }
    At4[kq * 129 + r] = make_float4(v0, v1, v2, v3);
  }
  STAGE_W(w1, 64, 24, 23)
  __syncthreads();
  int col = tid & 7, rowb = tid >> 3;
  int j0 = col * 8;
  float acc[4][8];
  ACC_INIT(b1)
  GEMM_KLOOP(6)
  __syncthreads();   // everyone done reading At4(features) + Wt(w1)
  // relu(h1) -> At4 in fragment layout (kq = col*2, col*2+1; rows rowb+32i)
#pragma unroll
  for (int i = 0; i < 4; ++i) {
    int rl = rowb + 32 * i;
    At4[(col * 2) * 129 + rl] =
        make_float4(fmaxf(acc[i][0], 0.f), fmaxf(acc[i][1], 0.f),
                    fmaxf(acc[i][2], 0.f), fmaxf(acc[i][3], 0.f));
    At4[(col * 2 + 1) * 129 + rl] =
        make_float4(fmaxf(acc[i][4], 0.f), fmaxf(acc[i][5], 0.f),
                    fmaxf(acc[i][6], 0.f), fmaxf(acc[i][7], 0.f));
  }
  STAGE_W(w2, 64, 64, 64)
  __syncthreads();
  ACC_INIT(b2)
  GEMM_KLOOP(16)
  STORE_C(hout, 64, false, false)
}

// ---------------- Dual GEMM via blockIdx.y: y=0 -> Cl = A@Wl+bl, y=1 -> Cr = A@Wr+br ----
__global__ __launch_bounds__(256, 3) void k_gemm2(
    const float* __restrict__ A,
    const float* __restrict__ Wl, const float* __restrict__ bl,
    const float* __restrict__ Wr, const float* __restrict__ br,
    float* __restrict__ Cl, float* __restrict__ Cr) {
  __shared__ float4 At4[16 * 129];
  __shared__ float Wt[64 * 64];
  int tid = threadIdx.x;
  int nb = blockIdx.x * 128;
  const float* W = blockIdx.y ? Wr : Wl;
  const float* b = blockIdx.y ? br : bl;
  float* C       = blockIdx.y ? Cr : Cl;
  STAGE_A(A, 64, 16)
  STAGE_W(W, 64, 64, 64)
  __syncthreads();
  int col = tid & 7, rowb = tid >> 3;
  int j0 = col * 8;
  float acc[4][8];
  ACC_INIT(b)
  GEMM_KLOOP(16)
  STORE_C(C, 64, false, false)
}

// ---------------- Fully fused GRU: gi(3 chunks) + gh(3 chunks) + gates, NO gbuf --------
__global__ __launch_bounds__(256, 3) void k_gru(
    const float* __restrict__ hA, const float* __restrict__ hs,
    const float* __restrict__ wih, const float* __restrict__ bih,
    const float* __restrict__ whh, const float* __restrict__ bhh,
    float* __restrict__ outnh) {
  __shared__ float4 At4[16 * 129];
  __shared__ float Wt[64 * 64];
  int tid = threadIdx.x;
  int nb = blockIdx.x * 128;
  int col = tid & 7, rowb = tid >> 3;
  int j0 = col * 8;
  float g0[4][8], g1[4][8], g2[4][8];
  // ---- phase 1: gi = hA @ wih + bih (3 chunks, At4 = hA staged once) ----
  STAGE_A(hA, 64, 16)
  STAGE_W(wih + 0, 192, 64, 64)
  __syncthreads();
  { auto& acc = g0; ACC_INIT(bih + 0) GEMM_KLOOP(16) }
  __syncthreads();
  STAGE_W(wih + 64, 192, 64, 64)
  __syncthreads();
  { auto& acc = g1; ACC_INIT(bih + 64) GEMM_KLOOP(16) }
  __syncthreads();
  STAGE_W(wih + 128, 192, 64, 64)
  __syncthreads();
  { auto& acc = g2; ACC_INIT(bih + 128) GEMM_KLOOP(16) }
  __syncthreads();   // done with At4 = hA
  // ---- phase 2: gh chunks (At4 = hs), fold into gates progressively ----
  STAGE_A(hs, 64, 16)
  STAGE_W(whh + 0, 192, 64, 64)
  __syncthreads();
  float gh[4][8];
  { auto& acc = gh; ACC_INIT(bhh + 0) GEMM_KLOOP(16) }
#pragma unroll
  for (int i = 0; i < 4; ++i)
#pragma unroll
    for (int u = 0; u < 8; ++u)
      g0[i][u] = 1.f / (1.f + __expf(-(g0[i][u] + gh[i][u])));   // r
  __syncthreads();
  STAGE_W(whh + 64, 192, 64, 64)
  __syncthreads();
  { auto& acc = gh; ACC_INIT(bhh + 64) GEMM_KLOOP(16) }
#pragma unroll
  for (int i = 0; i < 4; ++i)
#pragma unroll
    for (int u = 0; u < 8; ++u)
      g1[i][u] = 1.f / (1.f + __expf(-(g1[i][u] + gh[i][u])));   // z
  __syncthreads();
  STAGE_W(whh + 128, 192, 64, 64)
  __syncthreads();
  { auto& acc = gh; ACC_INIT(bhh + 128) GEMM_KLOOP(16) }
#pragma unroll
  for (int i = 0; i < 4; ++i)
#pragma unroll
    for (int u = 0; u < 8; ++u)
      g2[i][u] = tanhf(g2[i][u] + g0[i][u] * gh[i][u]);          // n
  // ---- epilogue: out = (1-z)*n + z*hs  (hs read from LDS tile) ----
#pragma unroll
  for (int i = 0; i < 4; ++i) {
    int node = nb + rowb + 32 * i;
    if (node < N_) {
      int rl = rowb + 32 * i;
      float4 s0 = At4[(col * 2) * 129 + rl];
      float4 s1 = At4[(col * 2 + 1) * 129 + rl];
      float q0 = (1.f - g1[i][0]) * g2[i][0] + g1[i][0] * s0.x;
      float q1 = (1.f - g1[i][1]) * g2[i][1] + g1[i][1] * s0.y;
      float q2 = (1.f - g1[i][2]) * g2[i][2] + g1[i][2] * s0.z;
      float q3 = (1.f - g1[i][3]) * g2[i][3] + g1[i][3] * s0.w;
      float q4 = (1.f - g1[i][4]) * g2[i][4] + g1[i][4] * s1.x;
      float q5 = (1.f - g1[i][5]) * g2[i][5] + g1[i][5] * s1.y;
      float q6 = (1.f - g1[i][6]) * g2[i][6] + g1[i][6] * s1.z;
      float q7 = (1.f - g1[i][7]) * g2[i][7] + g1[i][7] * s1.w;
      float* op = outnh + (size_t)node * 64 + j0;
      *(float4*)op = make_float4(q0, q1, q2, q3);
      *(float4*)(op + 4) = make_float4(q4, q5, q6, q7);
    }
  }
}

// ---------------- Decoder: GEMM(relu) + layer-2 epilogue through LDS ----------------
__global__ __launch_bounds__(256, 3) void k_dec(
    const float* __restrict__ A,
    const float* __restrict__ w1, const float* __restrict__ b1,
    const float* __restrict__ w2, const float* __restrict__ b2,
    float* __restrict__ out) {
  __shared__ __align__(16) float pool[8320];   // At4 (33,024B) then dtile (33,280B)
  __shared__ float Wt[64 * 64];
  float4* At4 = (float4*)pool;
  float* dtile = pool;                          // aliased; separated by barriers
  int tid = threadIdx.x;
  int nb = blockIdx.x * 128;
  STAGE_A(A, 64, 16)
  STAGE_W(w1, 64, 64, 64)
  __syncthreads();
  int col = tid & 7, rowb = tid >> 3;
  int j0 = col * 8;
  float acc[4][8];
  ACC_INIT(b1)
  GEMM_KLOOP(16)
  __syncthreads();   // everyone done reading At4 before aliasing as dtile
#pragma unroll
  for (int i = 0; i < 4; ++i) {
    int rl = rowb + 32 * i;
#pragma unroll
    for (int u = 0; u < 8; ++u) dtile[rl * 65 + j0 + u] = fmaxf(acc[i][u], 0.f);
  }
  __syncthreads();
  if (tid < 128) {
    int node = nb + tid;
    if (node < N_) {
      float o0 = b2[0], o1 = b2[1], o2 = b2[2], o3 = b2[3], o4 = b2[4], o5 = b2[5], o6 = b2[6];
#pragma unroll 1
      for (int k = 0; k < 64; ++k) {
        float xv = dtile[tid * 65 + k];
        o0 = fmaf(xv, w2[k * 7 + 0], o0);
        o1 = fmaf(xv, w2[k * 7 + 1], o1);
        o2 = fmaf(xv, w2[k * 7 + 2], o2);
        o3 = fmaf(xv, w2[k * 7 + 3], o3);
        o4 = fmaf(xv, w2[k * 7 + 4], o4);
        o5 = fmaf(xv, w2[k * 7 + 5], o5);
        o6 = fmaf(xv, w2[k * 7 + 6], o6);
      }
      float* op = out + (size_t)node * 7;
      op[0] = o0; op[1] = o1; op[2] = o2; op[3] = o3; op[4] = o4; op[5] = o5; op[6] = o6;
    }
  }
}

// ---------------- Fused GAT: one node per 64-thread block (CSR-ordered ex + dinv) ----
// ex written to exP[p] in CSR order (contiguous 64B per wave-iteration, fully
// combined) replacing the random 16B alpha scatter (~85 MB/dispatch write
// amplification). dinv is PER-HEAD: lanes (slot==0, q=0,4,8,12) store dinvN[v][0..3].
// k_alpha permutes to edge order afterwards. No exbuf/ebuf LDS, no CAP limit, no
// second edge pass.
template <bool RELU>
__global__ __launch_bounds__(64, 6) void k_fused(
    const int* __restrict__ off, const int2* __restrict__ csr_es,
    const float* __restrict__ eaA, const float* __restrict__ eaB,
    const float* __restrict__ xl, const float* __restrict__ xr,
    const float* __restrict__ we, const float* __restrict__ att,
    const float* __restrict__ bias,
    float* __restrict__ hout, float* __restrict__ exP, float* __restrict__ dinvN) {
  __shared__ float wes[6 * 64];     // 1536 B
  int lane = threadIdx.x & 63;
  int slot = lane >> 4;       // edge slot 0..3
  int q = lane & 15;          // channel quad
  int head = q >> 2;
  int sb = slot << 4;
  int v = blockIdx.x;

#pragma unroll
  for (int i = 0; i < 6; ++i) wes[i * 64 + lane] = we[i * 64 + lane];

  int p0 = off[v], p1 = off[v + 1];
  int cnt = p1 - p0;

  float att4[4], b4[4];
#pragma unroll
  for (int r = 0; r < 4; ++r) { att4[r] = att[q * 4 + r]; b4[r] = bias[q * 4 + r]; }

  float4 xr4 = *(const float4*)(xr + (size_t)v * 64 + q * 4);
  float num0 = 0.f, num1 = 0.f, num2 = 0.f, num3 = 0.f, den = 0.f;

  __syncthreads();  // wes visible

  // index prefetch one iteration ahead (breaks csr_es -> xl serial miss chain)
  int p = p0 + slot;
  int2 es = (p < p1) ? csr_es[p] : make_int2(0, 0);
  for (int base = 0; base < cnt; base += 4) {
    int pc = p0 + base + slot;
    bool valid = pc < p1;
    int s = es.y;
    int pn = pc + 4;
    int2 esn = (pn < p1) ? csr_es[pn] : make_int2(0, 0);
    float ea = 0.f;
    if (valid) {
      if (q < 4)      ea = eaA[(size_t)pc * 4 + q];
      else if (q < 6) ea = eaB[(size_t)pc * 2 + (q - 4)];
    }
    float4 xls = valid ? *(const float4*)(xl + (size_t)s * 64 + q * 4)
                       : make_float4(0.f, 0.f, 0.f, 0.f);
    float m0 = xls.x + xr4.x, m1 = xls.y + xr4.y, m2 = xls.z + xr4.z, m3 = xls.w + xr4.w;
#pragma unroll
    for (int i = 0; i < 6; ++i) {
      float eai = __shfl(ea, sb + i);
      float4 w4 = *(const float4*)(wes + i * 64 + q * 4);
      m0 = fmaf(eai, w4.x, m0);
      m1 = fmaf(eai, w4.y, m1);
      m2 = fmaf(eai, w4.z, m2);
      m3 = fmaf(eai, w4.w, m3);
    }
    m0 = (m0 > 0.f) ? m0 : 0.2f * m0;
    m1 = (m1 > 0.f) ? m1 : 0.2f * m1;
    m2 = (m2 > 0.f) ? m2 : 0.2f * m2;
    m3 = (m3 > 0.f) ? m3 : 0.2f * m3;
    float t = m0 * att4[0];
    t = fmaf(m1, att4[1], t);
    t = fmaf(m2, att4[2], t);
    t = fmaf(m3, att4[3], t);
    t += __shfl_xor(t, 1);
    t += __shfl_xor(t, 2);
    float ex = valid ? __expf(t) : 0.f;
    den += ex;
    num0 = fmaf(xls.x, ex, num0);
    num1 = fmaf(xls.y, ex, num1);
    num2 = fmaf(xls.z, ex, num2);
    num3 = fmaf(xls.w, ex, num3);
    // CSR-ordered ex store: 16 writers cover one contiguous 64B region per iter
    if (valid && (lane & 3) == 0) exP[(size_t)pc * 4 + head] = ex;
    es = esn;
  }
  num0 += __shfl_xor(num0, 16); num0 += __shfl_xor(num0, 32);
  num1 += __shfl_xor(num1, 16); num1 += __shfl_xor(num1, 32);
  num2 += __shfl_xor(num2, 16); num2 += __shfl_xor(num2, 32);
  num3 += __shfl_xor(num3, 16); num3 += __shfl_xor(num3, 32);
  den  += __shfl_xor(den, 16);  den  += __shfl_xor(den, 32);
  float dinv = 1.f / (den + 1e-16f);   // per-head (den is head-specific per lane)
  float o0 = fmaf(num0, dinv, b4[0]);
  float o1 = fmaf(num1, dinv, b4[1]);
  float o2 = fmaf(num2, dinv, b4[2]);
  float o3 = fmaf(num3, dinv, b4[3]);
  if (RELU) {
    o0 = fmaxf(o0, 0.f); o1 = fmaxf(o1, 0.f); o2 = fmaxf(o2, 0.f); o3 = fmaxf(o3, 0.f);
  }
  if (slot == 0)
    *(float4*)(hout + (size_t)v * 64 + q * 4) = make_float4(o0, o1, o2, o3);
  // store all 4 per-head denominators (one lane per head)
  if (slot == 0 && (lane & 3) == 0) dinvN[(size_t)v * 4 + head] = dinv;
}

extern "C" void kernel_launch(void* const* d_in, const int* in_sizes, int n_in,
                              void* d_out, int out_size, void* d_ws, size_t ws_size,
                              hipStream_t stream) {
  const float* x      = (const float*)d_in[0];
  const int* ntype    = (const int*)d_in[1];
  const int* sid      = (const int*)d_in[2];
  const int* ei       = (const int*)d_in[3];
  const float* eattr  = (const float*)d_in[4];
  const float* hs     = (const float*)d_in[5];
  const float* temb   = (const float*)d_in[6];
  const float* semb   = (const float*)d_in[7];
  const float* enc_w1 = (const float*)d_in[8];
  const float* enc_b1 = (const float*)d_in[9];
  const float* enc_w2 = (const float*)d_in[10];
  const float* enc_b2 = (const float*)d_in[11];
  const float* g1_wl  = (const float*)d_in[12];
  const float* g1_bl  = (const float*)d_in[13];
  const float* g1_wr  = (const float*)d_in[14];
  const float* g1_br  = (const float*)d_in[15];
  const float* g1_we  = (const float*)d_in[16];
  const float* g1_att = (const float*)d_in[17];
  const float* g1_bias= (const float*)d_in[18];
  const float* g2_wl  = (const float*)d_in[19];
  const float* g2_bl  = (const float*)d_in[20];
  const float* g2_wr  = (const float*)d_in[21];
  const float* g2_br  = (const float*)d_in[22];
  const float* g2_we  = (const float*)d_in[23];
  const float* g2_att = (const float*)d_in[24];
  const float* g2_bias= (const float*)d_in[25];
  const float* gru_wih= (const float*)d_in[26];
  const float* gru_bih= (const float*)d_in[27];
  const float* gru_whh= (const float*)d_in[28];
  const float* gru_bhh= (const float*)d_in[29];
  const float* dec_w1 = (const float*)d_in[30];
  const float* dec_b1 = (const float*)d_in[31];
  const float* dec_w2 = (const float*)d_in[32];
  const float* dec_b2 = (const float*)d_in[33];

  float* ws = (float*)d_ws;
  float* hA = ws;               // N*64
  float* hB = hA + N_ * 64;     // N*64
  float* xl = hB + N_ * 64;     // N*64
  float* xr = xl + N_ * 64;     // N*64
  float* U  = xr + N_ * 64;     // N*64 -> eaA (E*4 floats = N*64 exactly)
  int* deg  = (int*)(U + N_ * 64);   // N
  int* off  = deg + N_;              // N+1
  int* cur  = off + N_ + 1;          // N
  int* bsum = cur + N_;              // 64 (pad -> csr_es 8B aligned)
  int2* csr_es = (int2*)(bsum + 64); // E pairs
  float2* eaB = (float2*)(csr_es + E_);  // E float2
  float* exP  = (float*)(eaB + E_);      // E*4 floats (CSR-ordered raw exp)
  int* pos    = (int*)(exP + (size_t)E_ * 4);  // E ints
  float* dinvN = (float*)(pos + E_);     // N*4 floats (per-head denominators)

  float4* eaA = (float4*)U;
  const int* dei = ei + E_;              // dst row of edge_index

  float* out0  = (float*)d_out;      // N*7
  float* outnh = out0 + N_ * 7;      // N*64
  float* outa1 = outnh + N_ * 64;    // E*4
  float* outa2 = outa1 + E_ * 4;     // E*4

  const int NB_SCAN = (N_ + 1023) / 1024;  // 49
  const int NB_GEMM = (N_ + 127) / 128;    // 391
  const int NB_E = (E_ + 255) / 256;       // 3125

  hipMemsetAsync(deg, 0, N_ * sizeof(int), stream);
  k_hist<<<NB_E, 256, 0, stream>>>(ei, deg);
  k_scan_blk<<<NB_SCAN, 1024, 0, stream>>>(deg, off, bsum);
  k_scan_top<<<1, 64, 0, stream>>>(bsum, NB_SCAN);
  k_scan_add<<<(N_ + 255) / 256, 256, 0, stream>>>(off, bsum, cur);
  k_scatter<<<NB_E, 256, 0, stream>>>(ei, cur, csr_es, pos);
  k_eaperm<<<NB_E, 256, 0, stream>>>(csr_es, eattr, eaA, eaB);

  // Encoder (both layers fused)
  k_enc<<<NB_GEMM, 256, 0, stream>>>(x, ntype, sid, temb, semb,
                                     enc_w1, enc_b1, enc_w2, enc_b2, hA);
  // GAT layer 1: hA -> hB (relu)
  k_gemm2<<<dim3(NB_GEMM, 2), 256, 0, stream>>>(hA, g1_wl, g1_bl, g1_wr, g1_br, xl, xr);
  k_fused<true><<<N_, 64, 0, stream>>>(off, csr_es, (const float*)eaA, (const float*)eaB,
                                       xl, xr, g1_we, g1_att, g1_bias, hB, exP, dinvN);
  k_alpha<<<NB_E, 256, 0, stream>>>(pos, dei, exP, dinvN, outa1);
  // GAT layer 2: hB -> hA (no relu)  (exP/dinvN reused)
  k_gemm2<<<dim3(NB_GEMM, 2), 256, 0, stream>>>(hB, g2_wl, g2_bl, g2_wr, g2_br, xl, xr);
  k_fused<false><<<N_, 64, 0, stream>>>(off, csr_es, (const float*)eaA, (const float*)eaB,
                                        xl, xr, g2_we, g2_att, g2_bias, hA, exP, dinvN);
  k_alpha<<<NB_E, 256, 0, stream>>>(pos, dei, exP, dinvN, outa2);
  // GRU fully fused (no gbuf)
  k_gru<<<NB_GEMM, 256, 0, stream>>>(hA, hs, gru_wih, gru_bih, gru_whh, gru_bhh, outnh);
  // Decoder (fused both layers)
  k_dec<<<NB_GEMM, 256, 0, stream>>>(outnh, dec_w1, dec_b1, dec_w2, dec_b2, out0);
}

// Round 12
// 519.498 us; speedup vs baseline: 1.0707x; 1.0707x over previous
//
#include <hip/hip_runtime.h>
#include <hip/hip_bf16.h>

static constexpr int N_ = 50000;
static constexpr int E_ = 800000;

// ================= shared GEMM building blocks (128 nodes x 64 cols tile) =================
// 256 thr: col=tid&7 (8 output quads), rowb=tid>>3 (32 rows); nodes rowb+32*i.
// At4 pitch 129 float4 -> conflict-free fragment reads. kg-loop NOT unrolled (spill guard).

#define GEMM_FMA_BLOCK(AV, W0, W1, ROW)                                              \
      acc[ROW][0]=fmaf(AV,W0.x,acc[ROW][0]); acc[ROW][1]=fmaf(AV,W0.y,acc[ROW][1]);  \
      acc[ROW][2]=fmaf(AV,W0.z,acc[ROW][2]); acc[ROW][3]=fmaf(AV,W0.w,acc[ROW][3]);  \
      acc[ROW][4]=fmaf(AV,W1.x,acc[ROW][4]); acc[ROW][5]=fmaf(AV,W1.y,acc[ROW][5]);  \
      acc[ROW][6]=fmaf(AV,W1.z,acc[ROW][6]); acc[ROW][7]=fmaf(AV,W1.w,acc[ROW][7]);

#define GEMM_KLOOP(KQc)                                                              \
  _Pragma("unroll 1")                                                                \
  for (int kg = 0; kg < (KQc); ++kg) {                                               \
    float4 a0 = At4[kg * 129 + rowb];                                                \
    float4 a1 = At4[kg * 129 + rowb + 32];                                           \
    float4 a2 = At4[kg * 129 + rowb + 64];                                           \
    float4 a3 = At4[kg * 129 + rowb + 96];                                           \
    _Pragma("unroll")                                                                \
    for (int t = 0; t < 4; ++t) {                                                    \
      float4 w0 = *(const float4*)(Wt + (kg * 4 + t) * 64 + j0);                     \
      float4 w1 = *(const float4*)(Wt + (kg * 4 + t) * 64 + j0 + 4);                 \
      float av0 = t==0?a0.x:t==1?a0.y:t==2?a0.z:a0.w;                                \
      float av1 = t==0?a1.x:t==1?a1.y:t==2?a1.z:a1.w;                                \
      float av2 = t==0?a2.x:t==1?a2.y:t==2?a2.z:a2.w;                                \
      float av3 = t==0?a3.x:t==1?a3.y:t==2?a3.z:a3.w;                                \
      GEMM_FMA_BLOCK(av0, w0, w1, 0)                                                 \
      GEMM_FMA_BLOCK(av1, w0, w1, 1)                                                 \
      GEMM_FMA_BLOCK(av2, w0, w1, 2)                                                 \
      GEMM_FMA_BLOCK(av3, w0, w1, 3)                                                 \
    }                                                                                \
  }

#define ACC_INIT(BPTR)                                                               \
  {                                                                                  \
    float4 b0v = *(const float4*)((BPTR) + j0);                                      \
    float4 b1v = *(const float4*)((BPTR) + j0 + 4);                                  \
    _Pragma("unroll")                                                                \
    for (int i = 0; i < 4; ++i) {                                                    \
      acc[i][0]=b0v.x; acc[i][1]=b0v.y; acc[i][2]=b0v.z; acc[i][3]=b0v.w;            \
      acc[i][4]=b1v.x; acc[i][5]=b1v.y; acc[i][6]=b1v.z; acc[i][7]=b1v.w;            \
    }                                                                                \
  }

#define STAGE_W(WPTR, LDW, KPADc, KREAL)                                             \
  for (int idx = tid; idx < (KPADc) * 16; idx += 256) {                              \
    int k = idx >> 4, jq = idx & 15;                                                 \
    float4 v = (k < (KREAL)) ? *(const float4*)((WPTR) + (size_t)k * (LDW) + jq * 4) \
                             : make_float4(0.f, 0.f, 0.f, 0.f);                      \
    *(float4*)(Wt + k * 64 + jq * 4) = v;                                            \
  }

#define STAGE_A(APTR, LDA, KQc)                                                      \
  for (int idx = tid; idx < 128 * (KQc); idx += 256) {                               \
    int r = idx / (KQc), kq = idx - r * (KQc);                                       \
    int node = nb + r;                                                               \
    float4 v = (node < N_) ? *(const float4*)((APTR) + (size_t)node * (LDA) + kq * 4)\
                           : make_float4(0.f, 0.f, 0.f, 0.f);                        \
    At4[kq * 129 + r] = v;                                                           \
  }

#define STORE_C(CPTR, LDC, RELUc, ACCc)                                              \
  _Pragma("unroll")                                                                  \
  for (int i = 0; i < 4; ++i) {                                                      \
    int node = nb + rowb + 32 * i;                                                   \
    if (node < N_) {                                                                 \
      float* cp = (CPTR) + (size_t)node * (LDC) + j0;                                \
      float o0=acc[i][0],o1=acc[i][1],o2=acc[i][2],o3=acc[i][3];                     \
      float o4=acc[i][4],o5=acc[i][5],o6=acc[i][6],o7=acc[i][7];                     \
      if (RELUc) { o0=fmaxf(o0,0.f);o1=fmaxf(o1,0.f);o2=fmaxf(o2,0.f);o3=fmaxf(o3,0.f); \
                   o4=fmaxf(o4,0.f);o5=fmaxf(o5,0.f);o6=fmaxf(o6,0.f);o7=fmaxf(o7,0.f); } \
      if (ACCc) { float4 c0=*(const float4*)cp; float4 c1=*(const float4*)(cp+4);    \
                  o0+=c0.x;o1+=c0.y;o2+=c0.z;o3+=c0.w;o4+=c1.x;o5+=c1.y;o6+=c1.z;o7+=c1.w; } \
      *(float4*)cp = make_float4(o0,o1,o2,o3);                                       \
      *(float4*)(cp+4) = make_float4(o4,o5,o6,o7);                                   \
    }                                                                                \
  }

// ---------------- CSR build ----------------
// Atomic paid ONCE: k_hist's atomicAdd return value IS the edge's rank within its
// destination bucket -> store it (coalesced); k_scatter becomes atomic-free streaming.
// rank ALIASES exP storage (rank dead after k_scatter; exP first written in k_fused)
// so the workspace footprint does NOT grow vs the proven R9 layout.
__global__ void k_hist(const int* __restrict__ ei, int* __restrict__ deg,
                       int* __restrict__ rank) {
  int e = blockIdx.x * blockDim.x + threadIdx.x;
  if (e < E_) rank[e] = atomicAdd(&deg[ei[E_ + e]], 1);
}

__global__ __launch_bounds__(1024) void k_scan_blk(const int* __restrict__ deg,
                                                   int* __restrict__ off,
                                                   int* __restrict__ bsum) {
  __shared__ int sm[1024];
  int t = threadIdx.x;
  int i = blockIdx.x * 1024 + t;
  int v = (i < N_) ? deg[i] : 0;
  sm[t] = v;
  __syncthreads();
  for (int s = 1; s < 1024; s <<= 1) {
    int u = (t >= s) ? sm[t - s] : 0;
    __syncthreads();
    sm[t] += u;
    __syncthreads();
  }
  if (i < N_) off[i] = sm[t] - v;
  if (t == 1023) bsum[blockIdx.x] = sm[t];
}

__global__ void k_scan_top(int* __restrict__ bsum, int nb) {
  int t = threadIdx.x;  // 64
  int v = (t < nb) ? bsum[t] : 0;
  int orig = v;
  for (int s = 1; s < 64; s <<= 1) {
    int u = __shfl_up(v, s);
    if (t >= s) v += u;
  }
  if (t < nb) bsum[t] = v - orig;
}

__global__ void k_scan_add(int* __restrict__ off, const int* __restrict__ bsum) {
  int i = blockIdx.x * blockDim.x + threadIdx.x;
  if (i < N_) off[i] = off[i] + bsum[i >> 10];
  if (i == 0) off[N_] = E_;
}

// Atomic-free scatter: p = off[d] + rank[e]. Reads coalesced (ei, rank) + one
// L2-resident random 4B (off[d]); writes csr_es[p] (random 8B, unavoidable) and
// pos[e] (coalesced) for the final alpha permute.
__global__ void k_scatter(const int* __restrict__ ei, const int* __restrict__ off,
                          const int* __restrict__ rank,
                          int2* __restrict__ csr_es, int* __restrict__ pos) {
  int e = blockIdx.x * blockDim.x + threadIdx.x;
  if (e < E_) {
    int s = ei[e];
    int d = ei[E_ + e];
    int p = off[d] + rank[e];
    csr_es[p] = make_int2(e, s);
    pos[e] = p;
  }
}

// Streaming permute of edge_attr into CSR order (random 24B eattr read paid ONCE).
__global__ void k_eaperm(const int2* __restrict__ csr_es, const float* __restrict__ eattr,
                         float4* __restrict__ eaA, float2* __restrict__ eaB) {
  int p = blockIdx.x * blockDim.x + threadIdx.x;
  if (p < E_) {
    int e = csr_es[p].x;
    const float* ep = eattr + (size_t)e * 6;
    eaA[p] = make_float4(ep[0], ep[1], ep[2], ep[3]);
    eaB[p] = make_float2(ep[4], ep[5]);
  }
}

// Final alpha materialization: alpha[e][h] = exP[pos[e]][h] * dinv[dst[e]][h].
// dinv is PER-HEAD. Writes coalesced by e; exP/dinvN random reads hit L3-resident
// buffers (12.8 MB + 0.8 MB).
__global__ void k_alpha(const int* __restrict__ pos, const int* __restrict__ dei,
                        const float* __restrict__ exP, const float* __restrict__ dinvN,
                        float* __restrict__ alpha) {
  int e = blockIdx.x * blockDim.x + threadIdx.x;
  if (e < E_) {
    int p = pos[e];
    int d = dei[e];
    float4 di = *(const float4*)(dinvN + (size_t)d * 4);
    float4 x4 = *(const float4*)(exP + (size_t)p * 4);
    *(float4*)(alpha + (size_t)e * 4) =
        make_float4(x4.x * di.x, x4.y * di.y, x4.z * di.z, x4.w * di.w);
  }
}

// ---------------- Fused encoder: relu(X24@W1+b1)@W2+b2 in ONE kernel ----------------
__device__ __forceinline__ float encval(int c, int node, int nt, int sd,
                                        const float* __restrict__ x,
                                        const float* __restrict__ temb,
                                        const float* __restrict__ semb) {
  if (c < 7) return x[node * 7 + c];
  if (c < 15) return temb[nt * 8 + c - 7];
  if (c < 23) return semb[sd * 8 + c - 15];
  return 0.f;
}

__global__ __launch_bounds__(256, 3) void k_enc(
    const float* __restrict__ x, const int* __restrict__ ntype, const int* __restrict__ sid,
    const float* __restrict__ temb, const float* __restrict__ semb,
    const float* __restrict__ w1, const float* __restrict__ b1,
    const float* __restrict__ w2, const float* __restrict__ b2,
    float* __restrict__ hout) {
  __shared__ float4 At4[16 * 129];   // phase1 uses rows kq=0..5; phase2 all 16
  __shared__ float Wt[64 * 64];
  int tid = threadIdx.x;
  int nb = blockIdx.x * 128;
  for (int idx = tid; idx < 128 * 6; idx += 256) {
    int r = idx / 6, kq = idx - r * 6;
    int node = nb + r;
    float v0 = 0.f, v1 = 0.f, v2 = 0.f, v3 = 0.f;
    if (node < N_) {
      int nt = ntype[node], sd = sid[node];
      int c = kq * 4;
      v0 = encval(c, node, nt, sd, x, temb, semb);
      v1 = encval(c + 1, node, nt, sd, x, temb, semb);
      v2 = encval(c + 2, node, nt, sd, x, temb, semb);
      v3 = encval(c + 3, node, nt, sd, x, temb, semb);
    }
    At4[kq * 129 + r] = make_float4(v0, v1, v2, v3);
  }
  STAGE_W(w1, 64, 24, 23)
  __syncthreads();
  int col = tid & 7, rowb = tid >> 3;
  int j0 = col * 8;
  float acc[4][8];
  ACC_INIT(b1)
  GEMM_KLOOP(6)
  __syncthreads();   // everyone done reading At4(features) + Wt(w1)
  // relu(h1) -> At4 in fragment layout (kq = col*2, col*2+1; rows rowb+32i)
#pragma unroll
  for (int i = 0; i < 4; ++i) {
    int rl = rowb + 32 * i;
    At4[(col * 2) * 129 + rl] =
        make_float4(fmaxf(acc[i][0], 0.f), fmaxf(acc[i][1], 0.f),
                    fmaxf(acc[i][2], 0.f), fmaxf(acc[i][3], 0.f));
    At4[(col * 2 + 1) * 129 + rl] =
        make_float4(fmaxf(acc[i][4], 0.f), fmaxf(acc[i][5], 0.f),
                    fmaxf(acc[i][6], 0.f), fmaxf(acc[i][7], 0.f));
  }
  STAGE_W(w2, 64, 64, 64)
  __syncthreads();
  ACC_INIT(b2)
  GEMM_KLOOP(16)
  STORE_C(hout, 64, false, false)
}

// ---------------- Dual GEMM via blockIdx.y: y=0 -> Cl = A@Wl+bl, y=1 -> Cr = A@Wr+br ----
__global__ __launch_bounds__(256, 3) void k_gemm2(
    const float* __restrict__ A,
    const float* __restrict__ Wl, const float* __restrict__ bl,
    const float* __restrict__ Wr, const float* __restrict__ br,
    float* __restrict__ Cl, float* __restrict__ Cr) {
  __shared__ float4 At4[16 * 129];
  __shared__ float Wt[64 * 64];
  int tid = threadIdx.x;
  int nb = blockIdx.x * 128;
  const float* W = blockIdx.y ? Wr : Wl;
  const float* b = blockIdx.y ? br : bl;
  float* C       = blockIdx.y ? Cr : Cl;
  STAGE_A(A, 64, 16)
  STAGE_W(W, 64, 64, 64)
  __syncthreads();
  int col = tid & 7, rowb = tid >> 3;
  int j0 = col * 8;
  float acc[4][8];
  ACC_INIT(b)
  GEMM_KLOOP(16)
  STORE_C(C, 64, false, false)
}

// ---------------- Fully fused GRU: gi(3 chunks) + gh(3 chunks) + gates, NO gbuf --------
__global__ __launch_bounds__(256, 3) void k_gru(
    const float* __restrict__ hA, const float* __restrict__ hs,
    const float* __restrict__ wih, const float* __restrict__ bih,
    const float* __restrict__ whh, const float* __restrict__ bhh,
    float* __restrict__ outnh) {
  __shared__ float4 At4[16 * 129];
  __shared__ float Wt[64 * 64];
  int tid = threadIdx.x;
  int nb = blockIdx.x * 128;
  int col = tid & 7, rowb = tid >> 3;
  int j0 = col * 8;
  float g0[4][8], g1[4][8], g2[4][8];
  // ---- phase 1: gi = hA @ wih + bih (3 chunks, At4 = hA staged once) ----
  STAGE_A(hA, 64, 16)
  STAGE_W(wih + 0, 192, 64, 64)
  __syncthreads();
  { auto& acc = g0; ACC_INIT(bih + 0) GEMM_KLOOP(16) }
  __syncthreads();
  STAGE_W(wih + 64, 192, 64, 64)
  __syncthreads();
  { auto& acc = g1; ACC_INIT(bih + 64) GEMM_KLOOP(16) }
  __syncthreads();
  STAGE_W(wih + 128, 192, 64, 64)
  __syncthreads();
  { auto& acc = g2; ACC_INIT(bih + 128) GEMM_KLOOP(16) }
  __syncthreads();   // done with At4 = hA
  // ---- phase 2: gh chunks (At4 = hs), fold into gates progressively ----
  STAGE_A(hs, 64, 16)
  STAGE_W(whh + 0, 192, 64, 64)
  __syncthreads();
  float gh[4][8];
  { auto& acc = gh; ACC_INIT(bhh + 0) GEMM_KLOOP(16) }
#pragma unroll
  for (int i = 0; i < 4; ++i)
#pragma unroll
    for (int u = 0; u < 8; ++u)
      g0[i][u] = 1.f / (1.f + __expf(-(g0[i][u] + gh[i][u])));   // r
  __syncthreads();
  STAGE_W(whh + 64, 192, 64, 64)
  __syncthreads();
  { auto& acc = gh; ACC_INIT(bhh + 64) GEMM_KLOOP(16) }
#pragma unroll
  for (int i = 0; i < 4; ++i)
#pragma unroll
    for (int u = 0; u < 8; ++u)
      g1[i][u] = 1.f / (1.f + __expf(-(g1[i][u] + gh[i][u])));   // z
  __syncthreads();
  STAGE_W(whh + 128, 192, 64, 64)
  __syncthreads();
  { auto& acc = gh; ACC_INIT(bhh + 128) GEMM_KLOOP(16) }
#pragma unroll
  for (int i = 0; i < 4; ++i)
#pragma unroll
    for (int u = 0; u < 8; ++u)
      g2[i][u] = tanhf(g2[i][u] + g0[i][u] * gh[i][u]);          // n
  // ---- epilogue: out = (1-z)*n + z*hs  (hs read from LDS tile) ----
#pragma unroll
  for (int i = 0; i < 4; ++i) {
    int node = nb + rowb + 32 * i;
    if (node < N_) {
      int rl = rowb + 32 * i;
      float4 s0 = At4[(col * 2) * 129 + rl];
      float4 s1 = At4[(col * 2 + 1) * 129 + rl];
      float q0 = (1.f - g1[i][0]) * g2[i][0] + g1[i][0] * s0.x;
      float q1 = (1.f - g1[i][1]) * g2[i][1] + g1[i][1] * s0.y;
      float q2 = (1.f - g1[i][2]) * g2[i][2] + g1[i][2] * s0.z;
      float q3 = (1.f - g1[i][3]) * g2[i][3] + g1[i][3] * s0.w;
      float q4 = (1.f - g1[i][4]) * g2[i][4] + g1[i][4] * s1.x;
      float q5 = (1.f - g1[i][5]) * g2[i][5] + g1[i][5] * s1.y;
      float q6 = (1.f - g1[i][6]) * g2[i][6] + g1[i][6] * s1.z;
      float q7 = (1.f - g1[i][7]) * g2[i][7] + g1[i][7] * s1.w;
      float* op = outnh + (size_t)node * 64 + j0;
      *(float4*)op = make_float4(q0, q1, q2, q3);
      *(float4*)(op + 4) = make_float4(q4, q5, q6, q7);
    }
  }
}

// ---------------- Decoder: GEMM(relu) + layer-2 epilogue through LDS ----------------
__global__ __launch_bounds__(256, 3) void k_dec(
    const float* __restrict__ A,
    const float* __restrict__ w1, const float* __restrict__ b1,
    const float* __restrict__ w2, const float* __restrict__ b2,
    float* __restrict__ out) {
  __shared__ __align__(16) float pool[8320];   // At4 (33,024B) then dtile (33,280B)
  __shared__ float Wt[64 * 64];
  float4* At4 = (float4*)pool;
  float* dtile = pool;                          // aliased; separated by barriers
  int tid = threadIdx.x;
  int nb = blockIdx.x * 128;
  STAGE_A(A, 64, 16)
  STAGE_W(w1, 64, 64, 64)
  __syncthreads();
  int col = tid & 7, rowb = tid >> 3;
  int j0 = col * 8;
  float acc[4][8];
  ACC_INIT(b1)
  GEMM_KLOOP(16)
  __syncthreads();   // everyone done reading At4 before aliasing as dtile
#pragma unroll
  for (int i = 0; i < 4; ++i) {
    int rl = rowb + 32 * i;
#pragma unroll
    for (int u = 0; u < 8; ++u) dtile[rl * 65 + j0 + u] = fmaxf(acc[i][u], 0.f);
  }
  __syncthreads();
  if (tid < 128) {
    int node = nb + tid;
    if (node < N_) {
      float o0 = b2[0], o1 = b2[1], o2 = b2[2], o3 = b2[3], o4 = b2[4], o5 = b2[5], o6 = b2[6];
#pragma unroll 1
      for (int k = 0; k < 64; ++k) {
        float xv = dtile[tid * 65 + k];
        o0 = fmaf(xv, w2[k * 7 + 0], o0);
        o1 = fmaf(xv, w2[k * 7 + 1], o1);
        o2 = fmaf(xv, w2[k * 7 + 2], o2);
        o3 = fmaf(xv, w2[k * 7 + 3], o3);
        o4 = fmaf(xv, w2[k * 7 + 4], o4);
        o5 = fmaf(xv, w2[k * 7 + 5], o5);
        o6 = fmaf(xv, w2[k * 7 + 6], o6);
      }
      float* op = out + (size_t)node * 7;
      op[0] = o0; op[1] = o1; op[2] = o2; op[3] = o3; op[4] = o4; op[5] = o5; op[6] = o6;
    }
  }
}

// ---------------- Fused GAT: one node per 64-thread block (CSR-ordered ex + dinv) ----
// ex written to exP[p] in CSR order (contiguous 64B per wave-iteration, fully
// combined) replacing the random 16B alpha scatter. dinv is PER-HEAD: lanes
// (slot==0, q=0,4,8,12) store dinvN[v][0..3]. k_alpha permutes to edge order.
template <bool RELU>
__global__ __launch_bounds__(64, 6) void k_fused(
    const int* __restrict__ off, const int2* __restrict__ csr_es,
    const float* __restrict__ eaA, const float* __restrict__ eaB,
    const float* __restrict__ xl, const float* __restrict__ xr,
    const float* __restrict__ we, const float* __restrict__ att,
    const float* __restrict__ bias,
    float* __restrict__ hout, float* __restrict__ exP, float* __restrict__ dinvN) {
  __shared__ float wes[6 * 64];     // 1536 B
  int lane = threadIdx.x & 63;
  int slot = lane >> 4;       // edge slot 0..3
  int q = lane & 15;          // channel quad
  int head = q >> 2;
  int sb = slot << 4;
  int v = blockIdx.x;

#pragma unroll
  for (int i = 0; i < 6; ++i) wes[i * 64 + lane] = we[i * 64 + lane];

  int p0 = off[v], p1 = off[v + 1];
  int cnt = p1 - p0;

  float att4[4], b4[4];
#pragma unroll
  for (int r = 0; r < 4; ++r) { att4[r] = att[q * 4 + r]; b4[r] = bias[q * 4 + r]; }

  float4 xr4 = *(const float4*)(xr + (size_t)v * 64 + q * 4);
  float num0 = 0.f, num1 = 0.f, num2 = 0.f, num3 = 0.f, den = 0.f;

  __syncthreads();  // wes visible

  // index prefetch one iteration ahead (breaks csr_es -> xl serial miss chain)
  int p = p0 + slot;
  int2 es = (p < p1) ? csr_es[p] : make_int2(0, 0);
  for (int base = 0; base < cnt; base += 4) {
    int pc = p0 + base + slot;
    bool valid = pc < p1;
    int s = es.y;
    int pn = pc + 4;
    int2 esn = (pn < p1) ? csr_es[pn] : make_int2(0, 0);
    float ea = 0.f;
    if (valid) {
      if (q < 4)      ea = eaA[(size_t)pc * 4 + q];
      else if (q < 6) ea = eaB[(size_t)pc * 2 + (q - 4)];
    }
    float4 xls = valid ? *(const float4*)(xl + (size_t)s * 64 + q * 4)
                       : make_float4(0.f, 0.f, 0.f, 0.f);
    float m0 = xls.x + xr4.x, m1 = xls.y + xr4.y, m2 = xls.z + xr4.z, m3 = xls.w + xr4.w;
#pragma unroll
    for (int i = 0; i < 6; ++i) {
      float eai = __shfl(ea, sb + i);
      float4 w4 = *(const float4*)(wes + i * 64 + q * 4);
      m0 = fmaf(eai, w4.x, m0);
      m1 = fmaf(eai, w4.y, m1);
      m2 = fmaf(eai, w4.z, m2);
      m3 = fmaf(eai, w4.w, m3);
    }
    m0 = (m0 > 0.f) ? m0 : 0.2f * m0;
    m1 = (m1 > 0.f) ? m1 : 0.2f * m1;
    m2 = (m2 > 0.f) ? m2 : 0.2f * m2;
    m3 = (m3 > 0.f) ? m3 : 0.2f * m3;
    float t = m0 * att4[0];
    t = fmaf(m1, att4[1], t);
    t = fmaf(m2, att4[2], t);
    t = fmaf(m3, att4[3], t);
    t += __shfl_xor(t, 1);
    t += __shfl_xor(t, 2);
    float ex = valid ? __expf(t) : 0.f;
    den += ex;
    num0 = fmaf(xls.x, ex, num0);
    num1 = fmaf(xls.y, ex, num1);
    num2 = fmaf(xls.z, ex, num2);
    num3 = fmaf(xls.w, ex, num3);
    // CSR-ordered ex store: 16 writers cover one contiguous 64B region per iter
    if (valid && (lane & 3) == 0) exP[(size_t)pc * 4 + head] = ex;
    es = esn;
  }
  num0 += __shfl_xor(num0, 16); num0 += __shfl_xor(num0, 32);
  num1 += __shfl_xor(num1, 16); num1 += __shfl_xor(num1, 32);
  num2 += __shfl_xor(num2, 16); num2 += __shfl_xor(num2, 32);
  num3 += __shfl_xor(num3, 16); num3 += __shfl_xor(num3, 32);
  den  += __shfl_xor(den, 16);  den  += __shfl_xor(den, 32);
  float dinv = 1.f / (den + 1e-16f);   // per-head (den is head-specific per lane)
  float o0 = fmaf(num0, dinv, b4[0]);
  float o1 = fmaf(num1, dinv, b4[1]);
  float o2 = fmaf(num2, dinv, b4[2]);
  float o3 = fmaf(num3, dinv, b4[3]);
  if (RELU) {
    o0 = fmaxf(o0, 0.f); o1 = fmaxf(o1, 0.f); o2 = fmaxf(o2, 0.f); o3 = fmaxf(o3, 0.f);
  }
  if (slot == 0)
    *(float4*)(hout + (size_t)v * 64 + q * 4) = make_float4(o0, o1, o2, o3);
  // store all 4 per-head denominators (one lane per head)
  if (slot == 0 && (lane & 3) == 0) dinvN[(size_t)v * 4 + head] = dinv;
}

extern "C" void kernel_launch(void* const* d_in, const int* in_sizes, int n_in,
                              void* d_out, int out_size, void* d_ws, size_t ws_size,
                              hipStream_t stream) {
  const float* x      = (const float*)d_in[0];
  const int* ntype    = (const int*)d_in[1];
  const int* sid      = (const int*)d_in[2];
  const int* ei       = (const int*)d_in[3];
  const float* eattr  = (const float*)d_in[4];
  const float* hs     = (const float*)d_in[5];
  const float* temb   = (const float*)d_in[6];
  const float* semb   = (const float*)d_in[7];
  const float* enc_w1 = (const float*)d_in[8];
  const float* enc_b1 = (const float*)d_in[9];
  const float* enc_w2 = (const float*)d_in[10];
  const float* enc_b2 = (const float*)d_in[11];
  const float* g1_wl  = (const float*)d_in[12];
  const float* g1_bl  = (const float*)d_in[13];
  const float* g1_wr  = (const float*)d_in[14];
  const float* g1_br  = (const float*)d_in[15];
  const float* g1_we  = (const float*)d_in[16];
  const float* g1_att = (const float*)d_in[17];
  const float* g1_bias= (const float*)d_in[18];
  const float* g2_wl  = (const float*)d_in[19];
  const float* g2_bl  = (const float*)d_in[20];
  const float* g2_wr  = (const float*)d_in[21];
  const float* g2_br  = (const float*)d_in[22];
  const float* g2_we  = (const float*)d_in[23];
  const float* g2_att = (const float*)d_in[24];
  const float* g2_bias= (const float*)d_in[25];
  const float* gru_wih= (const float*)d_in[26];
  const float* gru_bih= (const float*)d_in[27];
  const float* gru_whh= (const float*)d_in[28];
  const float* gru_bhh= (const float*)d_in[29];
  const float* dec_w1 = (const float*)d_in[30];
  const float* dec_b1 = (const float*)d_in[31];
  const float* dec_w2 = (const float*)d_in[32];
  const float* dec_b2 = (const float*)d_in[33];

  float* ws = (float*)d_ws;
  float* hA = ws;               // N*64
  float* hB = hA + N_ * 64;     // N*64
  float* xl = hB + N_ * 64;     // N*64
  float* xr = xl + N_ * 64;     // N*64
  float* U  = xr + N_ * 64;     // N*64 -> eaA (E*4 floats = N*64 exactly)
  int* deg  = (int*)(U + N_ * 64);   // N
  int* off  = deg + N_;              // N+1
  int* bsum = off + N_ + 1;          // 64 (+1 pad -> csr_es 8B aligned)
  int2* csr_es = (int2*)(bsum + 65); // E pairs
  float2* eaB = (float2*)(csr_es + E_);  // E float2
  float* exP  = (float*)(eaB + E_);      // E*4 floats (CSR-ordered raw exp)
  int* pos    = (int*)(exP + (size_t)E_ * 4);  // E ints
  float* dinvN = (float*)(pos + E_);     // N*4 floats (per-head denominators)
  int* rank   = (int*)exP;               // E ints, ALIASES exP (disjoint lifetimes:
                                         // rank: k_hist->k_scatter; exP: k_fused->k_alpha)

  float4* eaA = (float4*)U;
  const int* dei = ei + E_;              // dst row of edge_index

  float* out0  = (float*)d_out;      // N*7
  float* outnh = out0 + N_ * 7;      // N*64
  float* outa1 = outnh + N_ * 64;    // E*4
  float* outa2 = outa1 + E_ * 4;     // E*4

  const int NB_SCAN = (N_ + 1023) / 1024;  // 49
  const int NB_GEMM = (N_ + 127) / 128;    // 391
  const int NB_E = (E_ + 255) / 256;       // 3125

  hipMemsetAsync(deg, 0, N_ * sizeof(int), stream);
  k_hist<<<NB_E, 256, 0, stream>>>(ei, deg, rank);
  k_scan_blk<<<NB_SCAN, 1024, 0, stream>>>(deg, off, bsum);
  k_scan_top<<<1, 64, 0, stream>>>(bsum, NB_SCAN);
  k_scan_add<<<(N_ + 255) / 256, 256, 0, stream>>>(off, bsum);
  k_scatter<<<NB_E, 256, 0, stream>>>(ei, off, rank, csr_es, pos);
  k_eaperm<<<NB_E, 256, 0, stream>>>(csr_es, eattr, eaA, eaB);

  // Encoder (both layers fused)
  k_enc<<<NB_GEMM, 256, 0, stream>>>(x, ntype, sid, temb, semb,
                                     enc_w1, enc_b1, enc_w2, enc_b2, hA);
  // GAT layer 1: hA -> hB (relu)
  k_gemm2<<<dim3(NB_GEMM, 2), 256, 0, stream>>>(hA, g1_wl, g1_bl, g1_wr, g1_br, xl, xr);
  k_fused<true><<<N_, 64, 0, stream>>>(off, csr_es, (const float*)eaA, (const float*)eaB,
                                       xl, xr, g1_we, g1_att, g1_bias, hB, exP, dinvN);
  k_alpha<<<NB_E, 256, 0, stream>>>(pos, dei, exP, dinvN, outa1);
  // GAT layer 2: hB -> hA (no relu)  (exP/dinvN reused)
  k_gemm2<<<dim3(NB_GEMM, 2), 256, 0, stream>>>(hB, g2_wl, g2_bl, g2_wr, g2_br, xl, xr);
  k_fused<false><<<N_, 64, 0, stream>>>(off, csr_es, (const float*)eaA, (const float*)eaB,
                                        xl, xr, g2_we, g2_att, g2_bias, hA, exP, dinvN);
  k_alpha<<<NB_E, 256, 0, stream>>>(pos, dei, exP, dinvN, outa2);
  // GRU fully fused (no gbuf)
  k_gru<<<NB_GEMM, 256, 0, stream>>>(hA, hs, gru_wih, gru_bih, gru_whh, gru_bhh, outnh);
  // Decoder (fused both layers)
  k_dec<<<NB_GEMM, 256, 0, stream>>>(outnh, dec_w1, dec_b1, dec_w2, dec_b2, out0);
}

// Round 13
// 507.077 us; speedup vs baseline: 1.0970x; 1.0245x over previous
//
#include <hip/hip_runtime.h>
#include <hip/hip_bf16.h>

static constexpr int N_ = 50000;
static constexpr int E_ = 800000;

// ================= shared GEMM building blocks (128 nodes x 64 cols tile) =================
// 256 thr: col=tid&7 (8 output quads), rowb=tid>>3 (32 rows); nodes rowb+32*i.
// At4 pitch 129 float4 -> conflict-free fragment reads. kg-loop NOT unrolled (spill guard).

#define GEMM_FMA_BLOCK(AV, W0, W1, ROW)                                              \
      acc[ROW][0]=fmaf(AV,W0.x,acc[ROW][0]); acc[ROW][1]=fmaf(AV,W0.y,acc[ROW][1]);  \
      acc[ROW][2]=fmaf(AV,W0.z,acc[ROW][2]); acc[ROW][3]=fmaf(AV,W0.w,acc[ROW][3]);  \
      acc[ROW][4]=fmaf(AV,W1.x,acc[ROW][4]); acc[ROW][5]=fmaf(AV,W1.y,acc[ROW][5]);  \
      acc[ROW][6]=fmaf(AV,W1.z,acc[ROW][6]); acc[ROW][7]=fmaf(AV,W1.w,acc[ROW][7]);

#define GEMM_KLOOP(KQc)                                                              \
  _Pragma("unroll 1")                                                                \
  for (int kg = 0; kg < (KQc); ++kg) {                                               \
    float4 a0 = At4[kg * 129 + rowb];                                                \
    float4 a1 = At4[kg * 129 + rowb + 32];                                           \
    float4 a2 = At4[kg * 129 + rowb + 64];                                           \
    float4 a3 = At4[kg * 129 + rowb + 96];                                           \
    _Pragma("unroll")                                                                \
    for (int t = 0; t < 4; ++t) {                                                    \
      float4 w0 = *(const float4*)(Wt + (kg * 4 + t) * 64 + j0);                     \
      float4 w1 = *(const float4*)(Wt + (kg * 4 + t) * 64 + j0 + 4);                 \
      float av0 = t==0?a0.x:t==1?a0.y:t==2?a0.z:a0.w;                                \
      float av1 = t==0?a1.x:t==1?a1.y:t==2?a1.z:a1.w;                                \
      float av2 = t==0?a2.x:t==1?a2.y:t==2?a2.z:a2.w;                                \
      float av3 = t==0?a3.x:t==1?a3.y:t==2?a3.z:a3.w;                                \
      GEMM_FMA_BLOCK(av0, w0, w1, 0)                                                 \
      GEMM_FMA_BLOCK(av1, w0, w1, 1)                                                 \
      GEMM_FMA_BLOCK(av2, w0, w1, 2)                                                 \
      GEMM_FMA_BLOCK(av3, w0, w1, 3)                                                 \
    }                                                                                \
  }

// 64-node tile variant (k_gru): pitch 65 float4, 2 rows/thread.
#define GEMM_KLOOP64(KQc)                                                            \
  _Pragma("unroll 1")                                                                \
  for (int kg = 0; kg < (KQc); ++kg) {                                               \
    float4 a0 = At4[kg * 65 + rowb];                                                 \
    float4 a1 = At4[kg * 65 + rowb + 32];                                            \
    _Pragma("unroll")                                                                \
    for (int t = 0; t < 4; ++t) {                                                    \
      float4 w0 = *(const float4*)(Wt + (kg * 4 + t) * 64 + j0);                     \
      float4 w1 = *(const float4*)(Wt + (kg * 4 + t) * 64 + j0 + 4);                 \
      float av0 = t==0?a0.x:t==1?a0.y:t==2?a0.z:a0.w;                                \
      float av1 = t==0?a1.x:t==1?a1.y:t==2?a1.z:a1.w;                                \
      GEMM_FMA_BLOCK(av0, w0, w1, 0)                                                 \
      GEMM_FMA_BLOCK(av1, w0, w1, 1)                                                 \
    }                                                                                \
  }

#define ACC_INIT(BPTR)                                                               \
  {                                                                                  \
    float4 b0v = *(const float4*)((BPTR) + j0);                                      \
    float4 b1v = *(const float4*)((BPTR) + j0 + 4);                                  \
    _Pragma("unroll")                                                                \
    for (int i = 0; i < 4; ++i) {                                                    \
      acc[i][0]=b0v.x; acc[i][1]=b0v.y; acc[i][2]=b0v.z; acc[i][3]=b0v.w;            \
      acc[i][4]=b1v.x; acc[i][5]=b1v.y; acc[i][6]=b1v.z; acc[i][7]=b1v.w;            \
    }                                                                                \
  }

#define ACC_INIT2(BPTR)                                                              \
  {                                                                                  \
    float4 b0v = *(const float4*)((BPTR) + j0);                                      \
    float4 b1v = *(const float4*)((BPTR) + j0 + 4);                                  \
    _Pragma("unroll")                                                                \
    for (int i = 0; i < 2; ++i) {                                                    \
      acc[i][0]=b0v.x; acc[i][1]=b0v.y; acc[i][2]=b0v.z; acc[i][3]=b0v.w;            \
      acc[i][4]=b1v.x; acc[i][5]=b1v.y; acc[i][6]=b1v.z; acc[i][7]=b1v.w;            \
    }                                                                                \
  }

#define STAGE_W(WPTR, LDW, KPADc, KREAL)                                             \
  for (int idx = tid; idx < (KPADc) * 16; idx += 256) {                              \
    int k = idx >> 4, jq = idx & 15;                                                 \
    float4 v = (k < (KREAL)) ? *(const float4*)((WPTR) + (size_t)k * (LDW) + jq * 4) \
                             : make_float4(0.f, 0.f, 0.f, 0.f);                      \
    *(float4*)(Wt + k * 64 + jq * 4) = v;                                            \
  }

#define STAGE_A(APTR, LDA, KQc)                                                      \
  for (int idx = tid; idx < 128 * (KQc); idx += 256) {                               \
    int r = idx / (KQc), kq = idx - r * (KQc);                                       \
    int node = nb + r;                                                               \
    float4 v = (node < N_) ? *(const float4*)((APTR) + (size_t)node * (LDA) + kq * 4)\
                           : make_float4(0.f, 0.f, 0.f, 0.f);                        \
    At4[kq * 129 + r] = v;                                                           \
  }

// 64-node tile stage: 1024 float4s, 4 per thread, coalesced over kq.
#define STAGE_A64(APTR)                                                              \
  for (int idx = tid; idx < 64 * 16; idx += 256) {                                   \
    int r = idx >> 4, kq = idx & 15;                                                 \
    int node = nb + r;                                                               \
    float4 v = (node < N_) ? *(const float4*)((APTR) + (size_t)node * 64 + kq * 4)   \
                           : make_float4(0.f, 0.f, 0.f, 0.f);                        \
    At4[kq * 65 + r] = v;                                                            \
  }

#define STORE_C(CPTR, LDC, RELUc, ACCc)                                              \
  _Pragma("unroll")                                                                  \
  for (int i = 0; i < 4; ++i) {                                                      \
    int node = nb + rowb + 32 * i;                                                   \
    if (node < N_) {                                                                 \
      float* cp = (CPTR) + (size_t)node * (LDC) + j0;                                \
      float o0=acc[i][0],o1=acc[i][1],o2=acc[i][2],o3=acc[i][3];                     \
      float o4=acc[i][4],o5=acc[i][5],o6=acc[i][6],o7=acc[i][7];                     \
      if (RELUc) { o0=fmaxf(o0,0.f);o1=fmaxf(o1,0.f);o2=fmaxf(o2,0.f);o3=fmaxf(o3,0.f); \
                   o4=fmaxf(o4,0.f);o5=fmaxf(o5,0.f);o6=fmaxf(o6,0.f);o7=fmaxf(o7,0.f); } \
      if (ACCc) { float4 c0=*(const float4*)cp; float4 c1=*(const float4*)(cp+4);    \
                  o0+=c0.x;o1+=c0.y;o2+=c0.z;o3+=c0.w;o4+=c1.x;o5+=c1.y;o6+=c1.z;o7+=c1.w; } \
      *(float4*)cp = make_float4(o0,o1,o2,o3);                                       \
      *(float4*)(cp+4) = make_float4(o4,o5,o6,o7);                                   \
    }                                                                                \
  }

// ---------------- CSR build ----------------
// Atomic paid ONCE: k_hist's atomicAdd return value IS the edge's rank within its
// destination bucket; k_scatter is atomic-free streaming. rank aliases exP storage.
__global__ void k_hist(const int* __restrict__ ei, int* __restrict__ deg,
                       int* __restrict__ rank) {
  int e = blockIdx.x * blockDim.x + threadIdx.x;
  if (e < E_) rank[e] = atomicAdd(&deg[ei[E_ + e]], 1);
}

__global__ __launch_bounds__(1024) void k_scan_blk(const int* __restrict__ deg,
                                                   int* __restrict__ off,
                                                   int* __restrict__ bsum) {
  __shared__ int sm[1024];
  int t = threadIdx.x;
  int i = blockIdx.x * 1024 + t;
  int v = (i < N_) ? deg[i] : 0;
  sm[t] = v;
  __syncthreads();
  for (int s = 1; s < 1024; s <<= 1) {
    int u = (t >= s) ? sm[t - s] : 0;
    __syncthreads();
    sm[t] += u;
    __syncthreads();
  }
  if (i < N_) off[i] = sm[t] - v;
  if (t == 1023) bsum[blockIdx.x] = sm[t];
}

__global__ void k_scan_top(int* __restrict__ bsum, int nb) {
  int t = threadIdx.x;  // 64
  int v = (t < nb) ? bsum[t] : 0;
  int orig = v;
  for (int s = 1; s < 64; s <<= 1) {
    int u = __shfl_up(v, s);
    if (t >= s) v += u;
  }
  if (t < nb) bsum[t] = v - orig;
}

__global__ void k_scan_add(int* __restrict__ off, const int* __restrict__ bsum) {
  int i = blockIdx.x * blockDim.x + threadIdx.x;
  if (i < N_) off[i] = off[i] + bsum[i >> 10];
  if (i == 0) off[N_] = E_;
}

__global__ void k_scatter(const int* __restrict__ ei, const int* __restrict__ off,
                          const int* __restrict__ rank,
                          int2* __restrict__ csr_es, int* __restrict__ pos) {
  int e = blockIdx.x * blockDim.x + threadIdx.x;
  if (e < E_) {
    int s = ei[e];
    int d = ei[E_ + e];
    int p = off[d] + rank[e];
    csr_es[p] = make_int2(e, s);
    pos[e] = p;
  }
}

// Streaming permute of edge_attr into CSR order (random 24B eattr read paid ONCE).
__global__ void k_eaperm(const int2* __restrict__ csr_es, const float* __restrict__ eattr,
                         float4* __restrict__ eaA, float2* __restrict__ eaB) {
  int p = blockIdx.x * blockDim.x + threadIdx.x;
  if (p < E_) {
    int e = csr_es[p].x;
    const float* ep = eattr + (size_t)e * 6;
    eaA[p] = make_float4(ep[0], ep[1], ep[2], ep[3]);
    eaB[p] = make_float2(ep[4], ep[5]);
  }
}

// Final alpha: alpha[e][h] = exP[pos[e]][h] * dinv[dst[e]][h] (dinv PER-HEAD).
__global__ void k_alpha(const int* __restrict__ pos, const int* __restrict__ dei,
                        const float* __restrict__ exP, const float* __restrict__ dinvN,
                        float* __restrict__ alpha) {
  int e = blockIdx.x * blockDim.x + threadIdx.x;
  if (e < E_) {
    int p = pos[e];
    int d = dei[e];
    float4 di = *(const float4*)(dinvN + (size_t)d * 4);
    float4 x4 = *(const float4*)(exP + (size_t)p * 4);
    *(float4*)(alpha + (size_t)e * 4) =
        make_float4(x4.x * di.x, x4.y * di.y, x4.z * di.z, x4.w * di.w);
  }
}

// ---------------- Fused encoder: relu(X24@W1+b1)@W2+b2 in ONE kernel ----------------
__device__ __forceinline__ float encval(int c, int node, int nt, int sd,
                                        const float* __restrict__ x,
                                        const float* __restrict__ temb,
                                        const float* __restrict__ semb) {
  if (c < 7) return x[node * 7 + c];
  if (c < 15) return temb[nt * 8 + c - 7];
  if (c < 23) return semb[sd * 8 + c - 15];
  return 0.f;
}

__global__ __launch_bounds__(256, 3) void k_enc(
    const float* __restrict__ x, const int* __restrict__ ntype, const int* __restrict__ sid,
    const float* __restrict__ temb, const float* __restrict__ semb,
    const float* __restrict__ w1, const float* __restrict__ b1,
    const float* __restrict__ w2, const float* __restrict__ b2,
    float* __restrict__ hout) {
  __shared__ float4 At4[16 * 129];   // phase1 uses rows kq=0..5; phase2 all 16
  __shared__ float Wt[64 * 64];
  int tid = threadIdx.x;
  int nb = blockIdx.x * 128;
  for (int idx = tid; idx < 128 * 6; idx += 256) {
    int r = idx / 6, kq = idx - r * 6;
    int node = nb + r;
    float v0 = 0.f, v1 = 0.f, v2 = 0.f, v3 = 0.f;
    if (node < N_) {
      int nt = ntype[node], sd = sid[node];
      int c = kq * 4;
      v0 = encval(c, node, nt, sd, x, temb, semb);
      v1 = encval(c + 1, node, nt, sd, x, temb, semb);
      v2 = encval(c + 2, node, nt, sd, x, temb, semb);
      v3 = encval(c + 3, node, nt, sd, x, temb, semb);
    }
    At4[kq * 129 + r] = make_float4(v0, v1, v2, v3);
  }
  STAGE_W(w1, 64, 24, 23)
  __syncthreads();
  int col = tid & 7, rowb = tid >> 3;
  int j0 = col * 8;
  float acc[4][8];
  ACC_INIT(b1)
  GEMM_KLOOP(6)
  __syncthreads();   // everyone done reading At4(features) + Wt(w1)
  // relu(h1) -> At4 in fragment layout (kq = col*2, col*2+1; rows rowb+32i)
#pragma unroll
  for (int i = 0; i < 4; ++i) {
    int rl = rowb + 32 * i;
    At4[(col * 2) * 129 + rl] =
        make_float4(fmaxf(acc[i][0], 0.f), fmaxf(acc[i][1], 0.f),
                    fmaxf(acc[i][2], 0.f), fmaxf(acc[i][3], 0.f));
    At4[(col * 2 + 1) * 129 + rl] =
        make_float4(fmaxf(acc[i][4], 0.f), fmaxf(acc[i][5], 0.f),
                    fmaxf(acc[i][6], 0.f), fmaxf(acc[i][7], 0.f));
  }
  STAGE_W(w2, 64, 64, 64)
  __syncthreads();
  ACC_INIT(b2)
  GEMM_KLOOP(16)
  STORE_C(hout, 64, false, false)
}

// ---------------- Dual GEMM via blockIdx.y: y=0 -> Cl = A@Wl+bl, y=1 -> Cr = A@Wr+br ----
__global__ __launch_bounds__(256, 3) void k_gemm2(
    const float* __restrict__ A,
    const float* __restrict__ Wl, const float* __restrict__ bl,
    const float* __restrict__ Wr, const float* __restrict__ br,
    float* __restrict__ Cl, float* __restrict__ Cr) {
  __shared__ float4 At4[16 * 129];
  __shared__ float Wt[64 * 64];
  int tid = threadIdx.x;
  int nb = blockIdx.x * 128;
  const float* W = blockIdx.y ? Wr : Wl;
  const float* b = blockIdx.y ? br : bl;
  float* C       = blockIdx.y ? Cr : Cl;
  STAGE_A(A, 64, 16)
  STAGE_W(W, 64, 64, 64)
  __syncthreads();
  int col = tid & 7, rowb = tid >> 3;
  int j0 = col * 8;
  float acc[4][8];
  ACC_INIT(b)
  GEMM_KLOOP(16)
  STORE_C(C, 64, false, false)
}

// ---------------- Fully fused GRU, 64-node tiles (R13) ----------------
// R12 counters: grid 391 -> 1.5 blocks/CU -> Occupancy 14%, plus 128 live gate
// floats at VGPR=84 -> scratch spill. 64-node tile: grid 782 (~3 blocks/CU),
// 64 live gate floats (no spill), LDS 33KB (4 blocks/CU LDS-wise).
__global__ __launch_bounds__(256, 4) void k_gru(
    const float* __restrict__ hA, const float* __restrict__ hs,
    const float* __restrict__ wih, const float* __restrict__ bih,
    const float* __restrict__ whh, const float* __restrict__ bhh,
    float* __restrict__ outnh) {
  __shared__ float4 At4[16 * 65];   // 16.6 KB
  __shared__ float Wt[64 * 64];     // 16 KB
  int tid = threadIdx.x;
  int nb = blockIdx.x * 64;
  int col = tid & 7, rowb = tid >> 3;
  int j0 = col * 8;
  float g0[2][8], g1[2][8], g2[2][8];
  // ---- phase 1: gi = hA @ wih + bih (3 chunks, At4 = hA staged once) ----
  STAGE_A64(hA)
  STAGE_W(wih + 0, 192, 64, 64)
  __syncthreads();
  { auto& acc = g0; ACC_INIT2(bih + 0) GEMM_KLOOP64(16) }
  __syncthreads();
  STAGE_W(wih + 64, 192, 64, 64)
  __syncthreads();
  { auto& acc = g1; ACC_INIT2(bih + 64) GEMM_KLOOP64(16) }
  __syncthreads();
  STAGE_W(wih + 128, 192, 64, 64)
  __syncthreads();
  { auto& acc = g2; ACC_INIT2(bih + 128) GEMM_KLOOP64(16) }
  __syncthreads();   // done with At4 = hA
  // ---- phase 2: gh chunks (At4 = hs), fold into gates progressively ----
  STAGE_A64(hs)
  STAGE_W(whh + 0, 192, 64, 64)
  __syncthreads();
  float gh[2][8];
  { auto& acc = gh; ACC_INIT2(bhh + 0) GEMM_KLOOP64(16) }
#pragma unroll
  for (int i = 0; i < 2; ++i)
#pragma unroll
    for (int u = 0; u < 8; ++u)
      g0[i][u] = 1.f / (1.f + __expf(-(g0[i][u] + gh[i][u])));   // r
  __syncthreads();
  STAGE_W(whh + 64, 192, 64, 64)
  __syncthreads();
  { auto& acc = gh; ACC_INIT2(bhh + 64) GEMM_KLOOP64(16) }
#pragma unroll
  for (int i = 0; i < 2; ++i)
#pragma unroll
    for (int u = 0; u < 8; ++u)
      g1[i][u] = 1.f / (1.f + __expf(-(g1[i][u] + gh[i][u])));   // z
  __syncthreads();
  STAGE_W(whh + 128, 192, 64, 64)
  __syncthreads();
  { auto& acc = gh; ACC_INIT2(bhh + 128) GEMM_KLOOP64(16) }
#pragma unroll
  for (int i = 0; i < 2; ++i)
#pragma unroll
    for (int u = 0; u < 8; ++u)
      g2[i][u] = tanhf(g2[i][u] + g0[i][u] * gh[i][u]);          // n
  // ---- epilogue: out = (1-z)*n + z*hs  (hs read from LDS tile) ----
#pragma unroll
  for (int i = 0; i < 2; ++i) {
    int node = nb + rowb + 32 * i;
    if (node < N_) {
      int rl = rowb + 32 * i;
      float4 s0 = At4[(col * 2) * 65 + rl];
      float4 s1 = At4[(col * 2 + 1) * 65 + rl];
      float q0 = (1.f - g1[i][0]) * g2[i][0] + g1[i][0] * s0.x;
      float q1 = (1.f - g1[i][1]) * g2[i][1] + g1[i][1] * s0.y;
      float q2 = (1.f - g1[i][2]) * g2[i][2] + g1[i][2] * s0.z;
      float q3 = (1.f - g1[i][3]) * g2[i][3] + g1[i][3] * s0.w;
      float q4 = (1.f - g1[i][4]) * g2[i][4] + g1[i][4] * s1.x;
      float q5 = (1.f - g1[i][5]) * g2[i][5] + g1[i][5] * s1.y;
      float q6 = (1.f - g1[i][6]) * g2[i][6] + g1[i][6] * s1.z;
      float q7 = (1.f - g1[i][7]) * g2[i][7] + g1[i][7] * s1.w;
      float* op = outnh + (size_t)node * 64 + j0;
      *(float4*)op = make_float4(q0, q1, q2, q3);
      *(float4*)(op + 4) = make_float4(q4, q5, q6, q7);
    }
  }
}

// ---------------- Decoder: GEMM(relu) + layer-2 epilogue through LDS ----------------
__global__ __launch_bounds__(256, 3) void k_dec(
    const float* __restrict__ A,
    const float* __restrict__ w1, const float* __restrict__ b1,
    const float* __restrict__ w2, const float* __restrict__ b2,
    float* __restrict__ out) {
  __shared__ __align__(16) float pool[8320];   // At4 (33,024B) then dtile (33,280B)
  __shared__ float Wt[64 * 64];
  float4* At4 = (float4*)pool;
  float* dtile = pool;                          // aliased; separated by barriers
  int tid = threadIdx.x;
  int nb = blockIdx.x * 128;
  STAGE_A(A, 64, 16)
  STAGE_W(w1, 64, 64, 64)
  __syncthreads();
  int col = tid & 7, rowb = tid >> 3;
  int j0 = col * 8;
  float acc[4][8];
  ACC_INIT(b1)
  GEMM_KLOOP(16)
  __syncthreads();   // everyone done reading At4 before aliasing as dtile
#pragma unroll
  for (int i = 0; i < 4; ++i) {
    int rl = rowb + 32 * i;
#pragma unroll
    for (int u = 0; u < 8; ++u) dtile[rl * 65 + j0 + u] = fmaxf(acc[i][u], 0.f);
  }
  __syncthreads();
  if (tid < 128) {
    int node = nb + tid;
    if (node < N_) {
      float o0 = b2[0], o1 = b2[1], o2 = b2[2], o3 = b2[3], o4 = b2[4], o5 = b2[5], o6 = b2[6];
#pragma unroll 1
      for (int k = 0; k < 64; ++k) {
        float xv = dtile[tid * 65 + k];
        o0 = fmaf(xv, w2[k * 7 + 0], o0);
        o1 = fmaf(xv, w2[k * 7 + 1], o1);
        o2 = fmaf(xv, w2[k * 7 + 2], o2);
        o3 = fmaf(xv, w2[k * 7 + 3], o3);
        o4 = fmaf(xv, w2[k * 7 + 4], o4);
        o5 = fmaf(xv, w2[k * 7 + 5], o5);
        o6 = fmaf(xv, w2[k * 7 + 6], o6);
      }
      float* op = out + (size_t)node * 7;
      op[0] = o0; op[1] = o1; op[2] = o2; op[3] = o3; op[4] = o4; op[5] = o5; op[6] = o6;
    }
  }
}

// ---------------- Fused GAT: one node per 64-thread block (CSR-ordered ex + dinv) ----
template <bool RELU>
__global__ __launch_bounds__(64, 6) void k_fused(
    const int* __restrict__ off, const int2* __restrict__ csr_es,
    const float* __restrict__ eaA, const float* __restrict__ eaB,
    const float* __restrict__ xl, const float* __restrict__ xr,
    const float* __restrict__ we, const float* __restrict__ att,
    const float* __restrict__ bias,
    float* __restrict__ hout, float* __restrict__ exP, float* __restrict__ dinvN) {
  __shared__ float wes[6 * 64];     // 1536 B
  int lane = threadIdx.x & 63;
  int slot = lane >> 4;       // edge slot 0..3
  int q = lane & 15;          // channel quad
  int head = q >> 2;
  int sb = slot << 4;
  int v = blockIdx.x;

#pragma unroll
  for (int i = 0; i < 6; ++i) wes[i * 64 + lane] = we[i * 64 + lane];

  int p0 = off[v], p1 = off[v + 1];
  int cnt = p1 - p0;

  float att4[4], b4[4];
#pragma unroll
  for (int r = 0; r < 4; ++r) { att4[r] = att[q * 4 + r]; b4[r] = bias[q * 4 + r]; }

  float4 xr4 = *(const float4*)(xr + (size_t)v * 64 + q * 4);
  float num0 = 0.f, num1 = 0.f, num2 = 0.f, num3 = 0.f, den = 0.f;

  __syncthreads();  // wes visible

  // index prefetch one iteration ahead (breaks csr_es -> xl serial miss chain)
  int p = p0 + slot;
  int2 es = (p < p1) ? csr_es[p] : make_int2(0, 0);
  for (int base = 0; base < cnt; base += 4) {
    int pc = p0 + base + slot;
    bool valid = pc < p1;
    int s = es.y;
    int pn = pc + 4;
    int2 esn = (pn < p1) ? csr_es[pn] : make_int2(0, 0);
    float ea = 0.f;
    if (valid) {
      if (q < 4)      ea = eaA[(size_t)pc * 4 + q];
      else if (q < 6) ea = eaB[(size_t)pc * 2 + (q - 4)];
    }
    float4 xls = valid ? *(const float4*)(xl + (size_t)s * 64 + q * 4)
                       : make_float4(0.f, 0.f, 0.f, 0.f);
    float m0 = xls.x + xr4.x, m1 = xls.y + xr4.y, m2 = xls.z + xr4.z, m3 = xls.w + xr4.w;
#pragma unroll
    for (int i = 0; i < 6; ++i) {
      float eai = __shfl(ea, sb + i);
      float4 w4 = *(const float4*)(wes + i * 64 + q * 4);
      m0 = fmaf(eai, w4.x, m0);
      m1 = fmaf(eai, w4.y, m1);
      m2 = fmaf(eai, w4.z, m2);
      m3 = fmaf(eai, w4.w, m3);
    }
    m0 = (m0 > 0.f) ? m0 : 0.2f * m0;
    m1 = (m1 > 0.f) ? m1 : 0.2f * m1;
    m2 = (m2 > 0.f) ? m2 : 0.2f * m2;
    m3 = (m3 > 0.f) ? m3 : 0.2f * m3;
    float t = m0 * att4[0];
    t = fmaf(m1, att4[1], t);
    t = fmaf(m2, att4[2], t);
    t = fmaf(m3, att4[3], t);
    t += __shfl_xor(t, 1);
    t += __shfl_xor(t, 2);
    float ex = valid ? __expf(t) : 0.f;
    den += ex;
    num0 = fmaf(xls.x, ex, num0);
    num1 = fmaf(xls.y, ex, num1);
    num2 = fmaf(xls.z, ex, num2);
    num3 = fmaf(xls.w, ex, num3);
    // CSR-ordered ex store: 16 writers cover one contiguous 64B region per iter
    if (valid && (lane & 3) == 0) exP[(size_t)pc * 4 + head] = ex;
    es = esn;
  }
  num0 += __shfl_xor(num0, 16); num0 += __shfl_xor(num0, 32);
  num1 += __shfl_xor(num1, 16); num1 += __shfl_xor(num1, 32);
  num2 += __shfl_xor(num2, 16); num2 += __shfl_xor(num2, 32);
  num3 += __shfl_xor(num3, 16); num3 += __shfl_xor(num3, 32);
  den  += __shfl_xor(den, 16);  den  += __shfl_xor(den, 32);
  float dinv = 1.f / (den + 1e-16f);   // per-head (den is head-specific per lane)
  float o0 = fmaf(num0, dinv, b4[0]);
  float o1 = fmaf(num1, dinv, b4[1]);
  float o2 = fmaf(num2, dinv, b4[2]);
  float o3 = fmaf(num3, dinv, b4[3]);
  if (RELU) {
    o0 = fmaxf(o0, 0.f); o1 = fmaxf(o1, 0.f); o2 = fmaxf(o2, 0.f); o3 = fmaxf(o3, 0.f);
  }
  if (slot == 0)
    *(float4*)(hout + (size_t)v * 64 + q * 4) = make_float4(o0, o1, o2, o3);
  // store all 4 per-head denominators (one lane per head)
  if (slot == 0 && (lane & 3) == 0) dinvN[(size_t)v * 4 + head] = dinv;
}

extern "C" void kernel_launch(void* const* d_in, const int* in_sizes, int n_in,
                              void* d_out, int out_size, void* d_ws, size_t ws_size,
                              hipStream_t stream) {
  const float* x      = (const float*)d_in[0];
  const int* ntype    = (const int*)d_in[1];
  const int* sid      = (const int*)d_in[2];
  const int* ei       = (const int*)d_in[3];
  const float* eattr  = (const float*)d_in[4];
  const float* hs     = (const float*)d_in[5];
  const float* temb   = (const float*)d_in[6];
  const float* semb   = (const float*)d_in[7];
  const float* enc_w1 = (const float*)d_in[8];
  const float* enc_b1 = (const float*)d_in[9];
  const float* enc_w2 = (const float*)d_in[10];
  const float* enc_b2 = (const float*)d_in[11];
  const float* g1_wl  = (const float*)d_in[12];
  const float* g1_bl  = (const float*)d_in[13];
  const float* g1_wr  = (const float*)d_in[14];
  const float* g1_br  = (const float*)d_in[15];
  const float* g1_we  = (const float*)d_in[16];
  const float* g1_att = (const float*)d_in[17];
  const float* g1_bias= (const float*)d_in[18];
  const float* g2_wl  = (const float*)d_in[19];
  const float* g2_bl  = (const float*)d_in[20];
  const float* g2_wr  = (const float*)d_in[21];
  const float* g2_br  = (const float*)d_in[22];
  const float* g2_we  = (const float*)d_in[23];
  const float* g2_att = (const float*)d_in[24];
  const float* g2_bias= (const float*)d_in[25];
  const float* gru_wih= (const float*)d_in[26];
  const float* gru_bih= (const float*)d_in[27];
  const float* gru_whh= (const float*)d_in[28];
  const float* gru_bhh= (const float*)d_in[29];
  const float* dec_w1 = (const float*)d_in[30];
  const float* dec_b1 = (const float*)d_in[31];
  const float* dec_w2 = (const float*)d_in[32];
  const float* dec_b2 = (const float*)d_in[33];

  float* ws = (float*)d_ws;
  float* hA = ws;               // N*64
  float* hB = hA + N_ * 64;     // N*64
  float* xl = hB + N_ * 64;     // N*64
  float* xr = xl + N_ * 64;     // N*64
  float* U  = xr + N_ * 64;     // N*64 -> eaA (E*4 floats = N*64 exactly)
  int* deg  = (int*)(U + N_ * 64);   // N
  int* off  = deg + N_;              // N+1
  int* bsum = off + N_ + 1;          // 64 (+1 pad -> csr_es 8B aligned)
  int2* csr_es = (int2*)(bsum + 65); // E pairs
  float2* eaB = (float2*)(csr_es + E_);  // E float2
  float* exP  = (float*)(eaB + E_);      // E*4 floats (CSR-ordered raw exp)
  int* pos    = (int*)(exP + (size_t)E_ * 4);  // E ints
  float* dinvN = (float*)(pos + E_);     // N*4 floats (per-head denominators)
  int* rank   = (int*)exP;               // E ints, ALIASES exP (disjoint lifetimes)

  float4* eaA = (float4*)U;
  const int* dei = ei + E_;              // dst row of edge_index

  float* out0  = (float*)d_out;      // N*7
  float* outnh = out0 + N_ * 7;      // N*64
  float* outa1 = outnh + N_ * 64;    // E*4
  float* outa2 = outa1 + E_ * 4;     // E*4

  const int NB_SCAN = (N_ + 1023) / 1024;  // 49
  const int NB_GEMM = (N_ + 127) / 128;    // 391
  const int NB_GRU  = (N_ + 63) / 64;      // 782
  const int NB_E = (E_ + 255) / 256;       // 3125

  hipMemsetAsync(deg, 0, N_ * sizeof(int), stream);
  k_hist<<<NB_E, 256, 0, stream>>>(ei, deg, rank);
  k_scan_blk<<<NB_SCAN, 1024, 0, stream>>>(deg, off, bsum);
  k_scan_top<<<1, 64, 0, stream>>>(bsum, NB_SCAN);
  k_scan_add<<<(N_ + 255) / 256, 256, 0, stream>>>(off, bsum);
  k_scatter<<<NB_E, 256, 0, stream>>>(ei, off, rank, csr_es, pos);
  k_eaperm<<<NB_E, 256, 0, stream>>>(csr_es, eattr, eaA, eaB);

  // Encoder (both layers fused)
  k_enc<<<NB_GEMM, 256, 0, stream>>>(x, ntype, sid, temb, semb,
                                     enc_w1, enc_b1, enc_w2, enc_b2, hA);
  // GAT layer 1: hA -> hB (relu)
  k_gemm2<<<dim3(NB_GEMM, 2), 256, 0, stream>>>(hA, g1_wl, g1_bl, g1_wr, g1_br, xl, xr);
  k_fused<true><<<N_, 64, 0, stream>>>(off, csr_es, (const float*)eaA, (const float*)eaB,
                                       xl, xr, g1_we, g1_att, g1_bias, hB, exP, dinvN);
  k_alpha<<<NB_E, 256, 0, stream>>>(pos, dei, exP, dinvN, outa1);
  // GAT layer 2: hB -> hA (no relu)  (exP/dinvN reused)
  k_gemm2<<<dim3(NB_GEMM, 2), 256, 0, stream>>>(hB, g2_wl, g2_bl, g2_wr, g2_br, xl, xr);
  k_fused<false><<<N_, 64, 0, stream>>>(off, csr_es, (const float*)eaA, (const float*)eaB,
                                        xl, xr, g2_we, g2_att, g2_bias, hA, exP, dinvN);
  k_alpha<<<NB_E, 256, 0, stream>>>(pos, dei, exP, dinvN, outa2);
  // GRU fully fused (64-node tiles, no gbuf)
  k_gru<<<NB_GRU, 256, 0, stream>>>(hA, hs, gru_wih, gru_bih, gru_whh, gru_bhh, outnh);
  // Decoder (fused both layers)
  k_dec<<<NB_GEMM, 256, 0, stream>>>(outnh, dec_w1, dec_b1, dec_w2, dec_b2, out0);
}

// Round 14
// 499.042 us; speedup vs baseline: 1.1146x; 1.0161x over previous
//
#include <hip/hip_runtime.h>
#include <hip/hip_bf16.h>

static constexpr int N_ = 50000;
static constexpr int E_ = 800000;

// bf16 pack/unpack (RNE) for the edge-gathered xl operand.
__device__ __forceinline__ unsigned short f2bf(float f) {
  unsigned int u = __float_as_uint(f);
  u = (u + 0x7FFFu + ((u >> 16) & 1u)) >> 16;
  return (unsigned short)u;
}
__device__ __forceinline__ float bf2f(unsigned short h) {
  return __uint_as_float((unsigned int)h << 16);
}

// ================= shared GEMM building blocks (128 nodes x 64 cols tile) =================
#define GEMM_FMA_BLOCK(AV, W0, W1, ROW)                                              \
      acc[ROW][0]=fmaf(AV,W0.x,acc[ROW][0]); acc[ROW][1]=fmaf(AV,W0.y,acc[ROW][1]);  \
      acc[ROW][2]=fmaf(AV,W0.z,acc[ROW][2]); acc[ROW][3]=fmaf(AV,W0.w,acc[ROW][3]);  \
      acc[ROW][4]=fmaf(AV,W1.x,acc[ROW][4]); acc[ROW][5]=fmaf(AV,W1.y,acc[ROW][5]);  \
      acc[ROW][6]=fmaf(AV,W1.z,acc[ROW][6]); acc[ROW][7]=fmaf(AV,W1.w,acc[ROW][7]);

#define GEMM_KLOOP(KQc)                                                              \
  _Pragma("unroll 1")                                                                \
  for (int kg = 0; kg < (KQc); ++kg) {                                               \
    float4 a0 = At4[kg * 129 + rowb];                                                \
    float4 a1 = At4[kg * 129 + rowb + 32];                                           \
    float4 a2 = At4[kg * 129 + rowb + 64];                                           \
    float4 a3 = At4[kg * 129 + rowb + 96];                                           \
    _Pragma("unroll")                                                                \
    for (int t = 0; t < 4; ++t) {                                                    \
      float4 w0 = *(const float4*)(Wt + (kg * 4 + t) * 64 + j0);                     \
      float4 w1 = *(const float4*)(Wt + (kg * 4 + t) * 64 + j0 + 4);                 \
      float av0 = t==0?a0.x:t==1?a0.y:t==2?a0.z:a0.w;                                \
      float av1 = t==0?a1.x:t==1?a1.y:t==2?a1.z:a1.w;                                \
      float av2 = t==0?a2.x:t==1?a2.y:t==2?a2.z:a2.w;                                \
      float av3 = t==0?a3.x:t==1?a3.y:t==2?a3.z:a3.w;                                \
      GEMM_FMA_BLOCK(av0, w0, w1, 0)                                                 \
      GEMM_FMA_BLOCK(av1, w0, w1, 1)                                                 \
      GEMM_FMA_BLOCK(av2, w0, w1, 2)                                                 \
      GEMM_FMA_BLOCK(av3, w0, w1, 3)                                                 \
    }                                                                                \
  }

// 64-node tile variant (k_gru): pitch 65 float4, 2 rows/thread.
#define GEMM_KLOOP64(KQc)                                                            \
  _Pragma("unroll 1")                                                                \
  for (int kg = 0; kg < (KQc); ++kg) {                                               \
    float4 a0 = At4[kg * 65 + rowb];                                                 \
    float4 a1 = At4[kg * 65 + rowb + 32];                                            \
    _Pragma("unroll")                                                                \
    for (int t = 0; t < 4; ++t) {                                                    \
      float4 w0 = *(const float4*)(Wt + (kg * 4 + t) * 64 + j0);                     \
      float4 w1 = *(const float4*)(Wt + (kg * 4 + t) * 64 + j0 + 4);                 \
      float av0 = t==0?a0.x:t==1?a0.y:t==2?a0.z:a0.w;                                \
      float av1 = t==0?a1.x:t==1?a1.y:t==2?a1.z:a1.w;                                \
      GEMM_FMA_BLOCK(av0, w0, w1, 0)                                                 \
      GEMM_FMA_BLOCK(av1, w0, w1, 1)                                                 \
    }                                                                                \
  }

#define ACC_INIT(BPTR)                                                               \
  {                                                                                  \
    float4 b0v = *(const float4*)((BPTR) + j0);                                      \
    float4 b1v = *(const float4*)((BPTR) + j0 + 4);                                  \
    _Pragma("unroll")                                                                \
    for (int i = 0; i < 4; ++i) {                                                    \
      acc[i][0]=b0v.x; acc[i][1]=b0v.y; acc[i][2]=b0v.z; acc[i][3]=b0v.w;            \
      acc[i][4]=b1v.x; acc[i][5]=b1v.y; acc[i][6]=b1v.z; acc[i][7]=b1v.w;            \
    }                                                                                \
  }

#define ACC_INIT2(BPTR)                                                              \
  {                                                                                  \
    float4 b0v = *(const float4*)((BPTR) + j0);                                      \
    float4 b1v = *(const float4*)((BPTR) + j0 + 4);                                  \
    _Pragma("unroll")                                                                \
    for (int i = 0; i < 2; ++i) {                                                    \
      acc[i][0]=b0v.x; acc[i][1]=b0v.y; acc[i][2]=b0v.z; acc[i][3]=b0v.w;            \
      acc[i][4]=b1v.x; acc[i][5]=b1v.y; acc[i][6]=b1v.z; acc[i][7]=b1v.w;            \
    }                                                                                \
  }

#define STAGE_W(WPTR, LDW, KPADc, KREAL)                                             \
  for (int idx = tid; idx < (KPADc) * 16; idx += 256) {                              \
    int k = idx >> 4, jq = idx & 15;                                                 \
    float4 v = (k < (KREAL)) ? *(const float4*)((WPTR) + (size_t)k * (LDW) + jq * 4) \
                             : make_float4(0.f, 0.f, 0.f, 0.f);                      \
    *(float4*)(Wt + k * 64 + jq * 4) = v;                                            \
  }

#define STAGE_A(APTR, LDA, KQc)                                                      \
  for (int idx = tid; idx < 128 * (KQc); idx += 256) {                               \
    int r = idx / (KQc), kq = idx - r * (KQc);                                       \
    int node = nb + r;                                                               \
    float4 v = (node < N_) ? *(const float4*)((APTR) + (size_t)node * (LDA) + kq * 4)\
                           : make_float4(0.f, 0.f, 0.f, 0.f);                        \
    At4[kq * 129 + r] = v;                                                           \
  }

#define STAGE_A64(APTR)                                                              \
  for (int idx = tid; idx < 64 * 16; idx += 256) {                                   \
    int r = idx >> 4, kq = idx & 15;                                                 \
    int node = nb + r;                                                               \
    float4 v = (node < N_) ? *(const float4*)((APTR) + (size_t)node * 64 + kq * 4)   \
                           : make_float4(0.f, 0.f, 0.f, 0.f);                        \
    At4[kq * 65 + r] = v;                                                            \
  }

#define STORE_C(CPTR, LDC, RELUc, ACCc)                                              \
  _Pragma("unroll")                                                                  \
  for (int i = 0; i < 4; ++i) {                                                      \
    int node = nb + rowb + 32 * i;                                                   \
    if (node < N_) {                                                                 \
      float* cp = (CPTR) + (size_t)node * (LDC) + j0;                                \
      float o0=acc[i][0],o1=acc[i][1],o2=acc[i][2],o3=acc[i][3];                     \
      float o4=acc[i][4],o5=acc[i][5],o6=acc[i][6],o7=acc[i][7];                     \
      if (RELUc) { o0=fmaxf(o0,0.f);o1=fmaxf(o1,0.f);o2=fmaxf(o2,0.f);o3=fmaxf(o3,0.f); \
                   o4=fmaxf(o4,0.f);o5=fmaxf(o5,0.f);o6=fmaxf(o6,0.f);o7=fmaxf(o7,0.f); } \
      if (ACCc) { float4 c0=*(const float4*)cp; float4 c1=*(const float4*)(cp+4);    \
                  o0+=c0.x;o1+=c0.y;o2+=c0.z;o3+=c0.w;o4+=c1.x;o5+=c1.y;o6+=c1.z;o7+=c1.w; } \
      *(float4*)cp = make_float4(o0,o1,o2,o3);                                       \
      *(float4*)(cp+4) = make_float4(o4,o5,o6,o7);                                   \
    }                                                                                \
  }

// ---------------- CSR build ----------------
__global__ void k_hist(const int* __restrict__ ei, int* __restrict__ deg,
                       int* __restrict__ rank) {
  int e = blockIdx.x * blockDim.x + threadIdx.x;
  if (e < E_) rank[e] = atomicAdd(&deg[ei[E_ + e]], 1);
}

__global__ __launch_bounds__(1024) void k_scan_blk(const int* __restrict__ deg,
                                                   int* __restrict__ off,
                                                   int* __restrict__ bsum) {
  __shared__ int sm[1024];
  int t = threadIdx.x;
  int i = blockIdx.x * 1024 + t;
  int v = (i < N_) ? deg[i] : 0;
  sm[t] = v;
  __syncthreads();
  for (int s = 1; s < 1024; s <<= 1) {
    int u = (t >= s) ? sm[t - s] : 0;
    __syncthreads();
    sm[t] += u;
    __syncthreads();
  }
  if (i < N_) off[i] = sm[t] - v;
  if (t == 1023) bsum[blockIdx.x] = sm[t];
}

__global__ void k_scan_top(int* __restrict__ bsum, int nb) {
  int t = threadIdx.x;  // 64
  int v = (t < nb) ? bsum[t] : 0;
  int orig = v;
  for (int s = 1; s < 64; s <<= 1) {
    int u = __shfl_up(v, s);
    if (t >= s) v += u;
  }
  if (t < nb) bsum[t] = v - orig;
}

__global__ void k_scan_add(int* __restrict__ off, const int* __restrict__ bsum) {
  int i = blockIdx.x * blockDim.x + threadIdx.x;
  if (i < N_) off[i] = off[i] + bsum[i >> 10];
  if (i == 0) off[N_] = E_;
}

__global__ void k_scatter(const int* __restrict__ ei, const int* __restrict__ off,
                          const int* __restrict__ rank,
                          int2* __restrict__ csr_es, int* __restrict__ pos) {
  int e = blockIdx.x * blockDim.x + threadIdx.x;
  if (e < E_) {
    int s = ei[e];
    int d = ei[E_ + e];
    int p = off[d] + rank[e];
    csr_es[p] = make_int2(e, s);
    pos[e] = p;
  }
}

// Streaming permute of edge_attr into CSR order (random 24B eattr read paid ONCE).
__global__ void k_eaperm(const int2* __restrict__ csr_es, const float* __restrict__ eattr,
                         float4* __restrict__ eaA, float2* __restrict__ eaB) {
  int p = blockIdx.x * blockDim.x + threadIdx.x;
  if (p < E_) {
    int e = csr_es[p].x;
    const float* ep = eattr + (size_t)e * 6;
    eaA[p] = make_float4(ep[0], ep[1], ep[2], ep[3]);
    eaB[p] = make_float2(ep[4], ep[5]);
  }
}

// Final alpha: alpha[e][h] = exP[pos[e]][h] * dinv[dst[e]][h] (dinv PER-HEAD).
__global__ void k_alpha(const int* __restrict__ pos, const int* __restrict__ dei,
                        const float* __restrict__ exP, const float* __restrict__ dinvN,
                        float* __restrict__ alpha) {
  int e = blockIdx.x * blockDim.x + threadIdx.x;
  if (e < E_) {
    int p = pos[e];
    int d = dei[e];
    float4 di = *(const float4*)(dinvN + (size_t)d * 4);
    float4 x4 = *(const float4*)(exP + (size_t)p * 4);
    *(float4*)(alpha + (size_t)e * 4) =
        make_float4(x4.x * di.x, x4.y * di.y, x4.z * di.z, x4.w * di.w);
  }
}

// ---------------- Fused encoder: relu(X24@W1+b1)@W2+b2 in ONE kernel ----------------
__device__ __forceinline__ float encval(int c, int node, int nt, int sd,
                                        const float* __restrict__ x,
                                        const float* __restrict__ temb,
                                        const float* __restrict__ semb) {
  if (c < 7) return x[node * 7 + c];
  if (c < 15) return temb[nt * 8 + c - 7];
  if (c < 23) return semb[sd * 8 + c - 15];
  return 0.f;
}

__global__ __launch_bounds__(256, 3) void k_enc(
    const float* __restrict__ x, const int* __restrict__ ntype, const int* __restrict__ sid,
    const float* __restrict__ temb, const float* __restrict__ semb,
    const float* __restrict__ w1, const float* __restrict__ b1,
    const float* __restrict__ w2, const float* __restrict__ b2,
    float* __restrict__ hout) {
  __shared__ float4 At4[16 * 129];
  __shared__ float Wt[64 * 64];
  int tid = threadIdx.x;
  int nb = blockIdx.x * 128;
  for (int idx = tid; idx < 128 * 6; idx += 256) {
    int r = idx / 6, kq = idx - r * 6;
    int node = nb + r;
    float v0 = 0.f, v1 = 0.f, v2 = 0.f, v3 = 0.f;
    if (node < N_) {
      int nt = ntype[node], sd = sid[node];
      int c = kq * 4;
      v0 = encval(c, node, nt, sd, x, temb, semb);
      v1 = encval(c + 1, node, nt, sd, x, temb, semb);
      v2 = encval(c + 2, node, nt, sd, x, temb, semb);
      v3 = encval(c + 3, node, nt, sd, x, temb, semb);
    }
    At4[kq * 129 + r] = make_float4(v0, v1, v2, v3);
  }
  STAGE_W(w1, 64, 24, 23)
  __syncthreads();
  int col = tid & 7, rowb = tid >> 3;
  int j0 = col * 8;
  float acc[4][8];
  ACC_INIT(b1)
  GEMM_KLOOP(6)
  __syncthreads();
#pragma unroll
  for (int i = 0; i < 4; ++i) {
    int rl = rowb + 32 * i;
    At4[(col * 2) * 129 + rl] =
        make_float4(fmaxf(acc[i][0], 0.f), fmaxf(acc[i][1], 0.f),
                    fmaxf(acc[i][2], 0.f), fmaxf(acc[i][3], 0.f));
    At4[(col * 2 + 1) * 129 + rl] =
        make_float4(fmaxf(acc[i][4], 0.f), fmaxf(acc[i][5], 0.f),
                    fmaxf(acc[i][6], 0.f), fmaxf(acc[i][7], 0.f));
  }
  STAGE_W(w2, 64, 64, 64)
  __syncthreads();
  ACC_INIT(b2)
  GEMM_KLOOP(16)
  STORE_C(hout, 64, false, false)
}

// ---------------- Dual GEMM via blockIdx.y ----------------
// y=0: xl = A@Wl+bl stored as BF16 (halves the k_fused gather payload AND this write);
// y=1: xr = A@Wr+br stored fp32 (read once per node, precision kept).
__global__ __launch_bounds__(256, 3) void k_gemm2(
    const float* __restrict__ A,
    const float* __restrict__ Wl, const float* __restrict__ bl,
    const float* __restrict__ Wr, const float* __restrict__ br,
    unsigned short* __restrict__ xlh, float* __restrict__ Cr) {
  __shared__ float4 At4[16 * 129];
  __shared__ float Wt[64 * 64];
  int tid = threadIdx.x;
  int nb = blockIdx.x * 128;
  const float* W = blockIdx.y ? Wr : Wl;
  const float* b = blockIdx.y ? br : bl;
  STAGE_A(A, 64, 16)
  STAGE_W(W, 64, 64, 64)
  __syncthreads();
  int col = tid & 7, rowb = tid >> 3;
  int j0 = col * 8;
  float acc[4][8];
  ACC_INIT(b)
  GEMM_KLOOP(16)
  if (blockIdx.y == 0) {
#pragma unroll
    for (int i = 0; i < 4; ++i) {
      int node = nb + rowb + 32 * i;
      if (node < N_) {
        unsigned short* cp = xlh + (size_t)node * 64 + j0;
        *(ushort4*)cp = make_ushort4(f2bf(acc[i][0]), f2bf(acc[i][1]),
                                     f2bf(acc[i][2]), f2bf(acc[i][3]));
        *(ushort4*)(cp + 4) = make_ushort4(f2bf(acc[i][4]), f2bf(acc[i][5]),
                                           f2bf(acc[i][6]), f2bf(acc[i][7]));
      }
    }
  } else {
    STORE_C(Cr, 64, false, false)
  }
}

// ---------------- Fully fused GRU, 64-node tiles ----------------
__global__ __launch_bounds__(256, 4) void k_gru(
    const float* __restrict__ hA, const float* __restrict__ hs,
    const float* __restrict__ wih, const float* __restrict__ bih,
    const float* __restrict__ whh, const float* __restrict__ bhh,
    float* __restrict__ outnh) {
  __shared__ float4 At4[16 * 65];
  __shared__ float Wt[64 * 64];
  int tid = threadIdx.x;
  int nb = blockIdx.x * 64;
  int col = tid & 7, rowb = tid >> 3;
  int j0 = col * 8;
  float g0[2][8], g1[2][8], g2[2][8];
  STAGE_A64(hA)
  STAGE_W(wih + 0, 192, 64, 64)
  __syncthreads();
  { auto& acc = g0; ACC_INIT2(bih + 0) GEMM_KLOOP64(16) }
  __syncthreads();
  STAGE_W(wih + 64, 192, 64, 64)
  __syncthreads();
  { auto& acc = g1; ACC_INIT2(bih + 64) GEMM_KLOOP64(16) }
  __syncthreads();
  STAGE_W(wih + 128, 192, 64, 64)
  __syncthreads();
  { auto& acc = g2; ACC_INIT2(bih + 128) GEMM_KLOOP64(16) }
  __syncthreads();
  STAGE_A64(hs)
  STAGE_W(whh + 0, 192, 64, 64)
  __syncthreads();
  float gh[2][8];
  { auto& acc = gh; ACC_INIT2(bhh + 0) GEMM_KLOOP64(16) }
#pragma unroll
  for (int i = 0; i < 2; ++i)
#pragma unroll
    for (int u = 0; u < 8; ++u)
      g0[i][u] = 1.f / (1.f + __expf(-(g0[i][u] + gh[i][u])));   // r
  __syncthreads();
  STAGE_W(whh + 64, 192, 64, 64)
  __syncthreads();
  { auto& acc = gh; ACC_INIT2(bhh + 64) GEMM_KLOOP64(16) }
#pragma unroll
  for (int i = 0; i < 2; ++i)
#pragma unroll
    for (int u = 0; u < 8; ++u)
      g1[i][u] = 1.f / (1.f + __expf(-(g1[i][u] + gh[i][u])));   // z
  __syncthreads();
  STAGE_W(whh + 128, 192, 64, 64)
  __syncthreads();
  { auto& acc = gh; ACC_INIT2(bhh + 128) GEMM_KLOOP64(16) }
#pragma unroll
  for (int i = 0; i < 2; ++i)
#pragma unroll
    for (int u = 0; u < 8; ++u)
      g2[i][u] = tanhf(g2[i][u] + g0[i][u] * gh[i][u]);          // n
#pragma unroll
  for (int i = 0; i < 2; ++i) {
    int node = nb + rowb + 32 * i;
    if (node < N_) {
      int rl = rowb + 32 * i;
      float4 s0 = At4[(col * 2) * 65 + rl];
      float4 s1 = At4[(col * 2 + 1) * 65 + rl];
      float q0 = (1.f - g1[i][0]) * g2[i][0] + g1[i][0] * s0.x;
      float q1 = (1.f - g1[i][1]) * g2[i][1] + g1[i][1] * s0.y;
      float q2 = (1.f - g1[i][2]) * g2[i][2] + g1[i][2] * s0.z;
      float q3 = (1.f - g1[i][3]) * g2[i][3] + g1[i][3] * s0.w;
      float q4 = (1.f - g1[i][4]) * g2[i][4] + g1[i][4] * s1.x;
      float q5 = (1.f - g1[i][5]) * g2[i][5] + g1[i][5] * s1.y;
      float q6 = (1.f - g1[i][6]) * g2[i][6] + g1[i][6] * s1.z;
      float q7 = (1.f - g1[i][7]) * g2[i][7] + g1[i][7] * s1.w;
      float* op = outnh + (size_t)node * 64 + j0;
      *(float4*)op = make_float4(q0, q1, q2, q3);
      *(float4*)(op + 4) = make_float4(q4, q5, q6, q7);
    }
  }
}

// ---------------- Decoder: GEMM(relu) + layer-2 epilogue through LDS ----------------
__global__ __launch_bounds__(256, 3) void k_dec(
    const float* __restrict__ A,
    const float* __restrict__ w1, const float* __restrict__ b1,
    const float* __restrict__ w2, const float* __restrict__ b2,
    float* __restrict__ out) {
  __shared__ __align__(16) float pool[8320];
  __shared__ float Wt[64 * 64];
  float4* At4 = (float4*)pool;
  float* dtile = pool;
  int tid = threadIdx.x;
  int nb = blockIdx.x * 128;
  STAGE_A(A, 64, 16)
  STAGE_W(w1, 64, 64, 64)
  __syncthreads();
  int col = tid & 7, rowb = tid >> 3;
  int j0 = col * 8;
  float acc[4][8];
  ACC_INIT(b1)
  GEMM_KLOOP(16)
  __syncthreads();
#pragma unroll
  for (int i = 0; i < 4; ++i) {
    int rl = rowb + 32 * i;
#pragma unroll
    for (int u = 0; u < 8; ++u) dtile[rl * 65 + j0 + u] = fmaxf(acc[i][u], 0.f);
  }
  __syncthreads();
  if (tid < 128) {
    int node = nb + tid;
    if (node < N_) {
      float o0 = b2[0], o1 = b2[1], o2 = b2[2], o3 = b2[3], o4 = b2[4], o5 = b2[5], o6 = b2[6];
#pragma unroll 1
      for (int k = 0; k < 64; ++k) {
        float xv = dtile[tid * 65 + k];
        o0 = fmaf(xv, w2[k * 7 + 0], o0);
        o1 = fmaf(xv, w2[k * 7 + 1], o1);
        o2 = fmaf(xv, w2[k * 7 + 2], o2);
        o3 = fmaf(xv, w2[k * 7 + 3], o3);
        o4 = fmaf(xv, w2[k * 7 + 4], o4);
        o5 = fmaf(xv, w2[k * 7 + 5], o5);
        o6 = fmaf(xv, w2[k * 7 + 6], o6);
      }
      float* op = out + (size_t)node * 7;
      op[0] = o0; op[1] = o1; op[2] = o2; op[3] = o3; op[4] = o4; op[5] = o5; op[6] = o6;
    }
  }
}

// ---------------- Fused GAT: one node per 64-thread block, BF16 xl gather ----------
// xl stored bf16 -> gather rows are 128B (was 256B): halves the dominant ~80MB
// cross-XCD refill term. CSR-ordered exP writes + per-head dinvN as in R13.
template <bool RELU>
__global__ __launch_bounds__(64, 6) void k_fused(
    const int* __restrict__ off, const int2* __restrict__ csr_es,
    const float* __restrict__ eaA, const float* __restrict__ eaB,
    const unsigned short* __restrict__ xlh, const float* __restrict__ xr,
    const float* __restrict__ we, const float* __restrict__ att,
    const float* __restrict__ bias,
    float* __restrict__ hout, float* __restrict__ exP, float* __restrict__ dinvN) {
  __shared__ float wes[6 * 64];     // 1536 B
  int lane = threadIdx.x & 63;
  int slot = lane >> 4;       // edge slot 0..3
  int q = lane & 15;          // channel quad
  int head = q >> 2;
  int sb = slot << 4;
  int v = blockIdx.x;

#pragma unroll
  for (int i = 0; i < 6; ++i) wes[i * 64 + lane] = we[i * 64 + lane];

  int p0 = off[v], p1 = off[v + 1];
  int cnt = p1 - p0;

  float att4[4], b4[4];
#pragma unroll
  for (int r = 0; r < 4; ++r) { att4[r] = att[q * 4 + r]; b4[r] = bias[q * 4 + r]; }

  float4 xr4 = *(const float4*)(xr + (size_t)v * 64 + q * 4);
  float num0 = 0.f, num1 = 0.f, num2 = 0.f, num3 = 0.f, den = 0.f;

  __syncthreads();  // wes visible

  // index prefetch one iteration ahead (breaks csr_es -> xl serial miss chain)
  int p = p0 + slot;
  int2 es = (p < p1) ? csr_es[p] : make_int2(0, 0);
  for (int base = 0; base < cnt; base += 4) {
    int pc = p0 + base + slot;
    bool valid = pc < p1;
    int s = es.y;
    int pn = pc + 4;
    int2 esn = (pn < p1) ? csr_es[pn] : make_int2(0, 0);
    float ea = 0.f;
    if (valid) {
      if (q < 4)      ea = eaA[(size_t)pc * 4 + q];
      else if (q < 6) ea = eaB[(size_t)pc * 2 + (q - 4)];
    }
    ushort4 h4 = valid ? *(const ushort4*)(xlh + (size_t)s * 64 + q * 4)
                       : make_ushort4(0, 0, 0, 0);
    float xl0 = bf2f(h4.x), xl1 = bf2f(h4.y), xl2 = bf2f(h4.z), xl3 = bf2f(h4.w);
    float m0 = xl0 + xr4.x, m1 = xl1 + xr4.y, m2 = xl2 + xr4.z, m3 = xl3 + xr4.w;
#pragma unroll
    for (int i = 0; i < 6; ++i) {
      float eai = __shfl(ea, sb + i);
      float4 w4 = *(const float4*)(wes + i * 64 + q * 4);
      m0 = fmaf(eai, w4.x, m0);
      m1 = fmaf(eai, w4.y, m1);
      m2 = fmaf(eai, w4.z, m2);
      m3 = fmaf(eai, w4.w, m3);
    }
    m0 = (m0 > 0.f) ? m0 : 0.2f * m0;
    m1 = (m1 > 0.f) ? m1 : 0.2f * m1;
    m2 = (m2 > 0.f) ? m2 : 0.2f * m2;
    m3 = (m3 > 0.f) ? m3 : 0.2f * m3;
    float t = m0 * att4[0];
    t = fmaf(m1, att4[1], t);
    t = fmaf(m2, att4[2], t);
    t = fmaf(m3, att4[3], t);
    t += __shfl_xor(t, 1);
    t += __shfl_xor(t, 2);
    float ex = valid ? __expf(t) : 0.f;
    den += ex;
    num0 = fmaf(xl0, ex, num0);
    num1 = fmaf(xl1, ex, num1);
    num2 = fmaf(xl2, ex, num2);
    num3 = fmaf(xl3, ex, num3);
    // CSR-ordered ex store: 16 writers cover one contiguous 64B region per iter
    if (valid && (lane & 3) == 0) exP[(size_t)pc * 4 + head] = ex;
    es = esn;
  }
  num0 += __shfl_xor(num0, 16); num0 += __shfl_xor(num0, 32);
  num1 += __shfl_xor(num1, 16); num1 += __shfl_xor(num1, 32);
  num2 += __shfl_xor(num2, 16); num2 += __shfl_xor(num2, 32);
  num3 += __shfl_xor(num3, 16); num3 += __shfl_xor(num3, 32);
  den  += __shfl_xor(den, 16);  den  += __shfl_xor(den, 32);
  float dinv = 1.f / (den + 1e-16f);   // per-head
  float o0 = fmaf(num0, dinv, b4[0]);
  float o1 = fmaf(num1, dinv, b4[1]);
  float o2 = fmaf(num2, dinv, b4[2]);
  float o3 = fmaf(num3, dinv, b4[3]);
  if (RELU) {
    o0 = fmaxf(o0, 0.f); o1 = fmaxf(o1, 0.f); o2 = fmaxf(o2, 0.f); o3 = fmaxf(o3, 0.f);
  }
  if (slot == 0)
    *(float4*)(hout + (size_t)v * 64 + q * 4) = make_float4(o0, o1, o2, o3);
  if (slot == 0 && (lane & 3) == 0) dinvN[(size_t)v * 4 + head] = dinv;
}

extern "C" void kernel_launch(void* const* d_in, const int* in_sizes, int n_in,
                              void* d_out, int out_size, void* d_ws, size_t ws_size,
                              hipStream_t stream) {
  const float* x      = (const float*)d_in[0];
  const int* ntype    = (const int*)d_in[1];
  const int* sid      = (const int*)d_in[2];
  const int* ei       = (const int*)d_in[3];
  const float* eattr  = (const float*)d_in[4];
  const float* hs     = (const float*)d_in[5];
  const float* temb   = (const float*)d_in[6];
  const float* semb   = (const float*)d_in[7];
  const float* enc_w1 = (const float*)d_in[8];
  const float* enc_b1 = (const float*)d_in[9];
  const float* enc_w2 = (const float*)d_in[10];
  const float* enc_b2 = (const float*)d_in[11];
  const float* g1_wl  = (const float*)d_in[12];
  const float* g1_bl  = (const float*)d_in[13];
  const float* g1_wr  = (const float*)d_in[14];
  const float* g1_br  = (const float*)d_in[15];
  const float* g1_we  = (const float*)d_in[16];
  const float* g1_att = (const float*)d_in[17];
  const float* g1_bias= (const float*)d_in[18];
  const float* g2_wl  = (const float*)d_in[19];
  const float* g2_bl  = (const float*)d_in[20];
  const float* g2_wr  = (const float*)d_in[21];
  const float* g2_br  = (const float*)d_in[22];
  const float* g2_we  = (const float*)d_in[23];
  const float* g2_att = (const float*)d_in[24];
  const float* g2_bias= (const float*)d_in[25];
  const float* gru_wih= (const float*)d_in[26];
  const float* gru_bih= (const float*)d_in[27];
  const float* gru_whh= (const float*)d_in[28];
  const float* gru_bhh= (const float*)d_in[29];
  const float* dec_w1 = (const float*)d_in[30];
  const float* dec_b1 = (const float*)d_in[31];
  const float* dec_w2 = (const float*)d_in[32];
  const float* dec_b2 = (const float*)d_in[33];

  float* ws = (float*)d_ws;
  float* hA = ws;               // N*64
  float* hB = hA + N_ * 64;     // N*64
  float* xl = hB + N_ * 64;     // N*64 (bf16 copy uses first half as ushort)
  float* xr = xl + N_ * 64;     // N*64
  float* U  = xr + N_ * 64;     // N*64 -> eaA (E*4 floats = N*64 exactly)
  int* deg  = (int*)(U + N_ * 64);   // N
  int* off  = deg + N_;              // N+1
  int* bsum = off + N_ + 1;          // 64 (+1 pad -> csr_es 8B aligned)
  int2* csr_es = (int2*)(bsum + 65); // E pairs
  float2* eaB = (float2*)(csr_es + E_);  // E float2
  float* exP  = (float*)(eaB + E_);      // E*4 floats (CSR-ordered raw exp)
  int* pos    = (int*)(exP + (size_t)E_ * 4);  // E ints
  float* dinvN = (float*)(pos + E_);     // N*4 floats (per-head denominators)
  int* rank   = (int*)exP;               // E ints, ALIASES exP (disjoint lifetimes)

  unsigned short* xlh = (unsigned short*)xl;  // bf16 xl, N*64 ushorts
  float4* eaA = (float4*)U;
  const int* dei = ei + E_;              // dst row of edge_index

  float* out0  = (float*)d_out;      // N*7
  float* outnh = out0 + N_ * 7;      // N*64
  float* outa1 = outnh + N_ * 64;    // E*4
  float* outa2 = outa1 + E_ * 4;     // E*4

  const int NB_SCAN = (N_ + 1023) / 1024;  // 49
  const int NB_GEMM = (N_ + 127) / 128;    // 391
  const int NB_GRU  = (N_ + 63) / 64;      // 782
  const int NB_E = (E_ + 255) / 256;       // 3125

  hipMemsetAsync(deg, 0, N_ * sizeof(int), stream);
  k_hist<<<NB_E, 256, 0, stream>>>(ei, deg, rank);
  k_scan_blk<<<NB_SCAN, 1024, 0, stream>>>(deg, off, bsum);
  k_scan_top<<<1, 64, 0, stream>>>(bsum, NB_SCAN);
  k_scan_add<<<(N_ + 255) / 256, 256, 0, stream>>>(off, bsum);
  k_scatter<<<NB_E, 256, 0, stream>>>(ei, off, rank, csr_es, pos);
  k_eaperm<<<NB_E, 256, 0, stream>>>(csr_es, eattr, eaA, eaB);

  // Encoder (both layers fused)
  k_enc<<<NB_GEMM, 256, 0, stream>>>(x, ntype, sid, temb, semb,
                                     enc_w1, enc_b1, enc_w2, enc_b2, hA);
  // GAT layer 1: hA -> hB (relu)
  k_gemm2<<<dim3(NB_GEMM, 2), 256, 0, stream>>>(hA, g1_wl, g1_bl, g1_wr, g1_br, xlh, xr);
  k_fused<true><<<N_, 64, 0, stream>>>(off, csr_es, (const float*)eaA, (const float*)eaB,
                                       xlh, xr, g1_we, g1_att, g1_bias, hB, exP, dinvN);
  k_alpha<<<NB_E, 256, 0, stream>>>(pos, dei, exP, dinvN, outa1);
  // GAT layer 2: hB -> hA (no relu)
  k_gemm2<<<dim3(NB_GEMM, 2), 256, 0, stream>>>(hB, g2_wl, g2_bl, g2_wr, g2_br, xlh, xr);
  k_fused<false><<<N_, 64, 0, stream>>>(off, csr_es, (const float*)eaA, (const float*)eaB,
                                        xlh, xr, g2_we, g2_att, g2_bias, hA, exP, dinvN);
  k_alpha<<<NB_E, 256, 0, stream>>>(pos, dei, exP, dinvN, outa2);
  // GRU fully fused (64-node tiles, no gbuf)
  k_gru<<<NB_GRU, 256, 0, stream>>>(hA, hs, gru_wih, gru_bih, gru_whh, gru_bhh, outnh);
  // Decoder (fused both layers)
  k_dec<<<NB_GEMM, 256, 0, stream>>>(outnh, dec_w1, dec_b1, dec_w2, dec_b2, out0);
}